// Round 1
// baseline (159.380 us; speedup 1.0000x reference)
//
#include <hip/hip_runtime.h>
#include <hip/hip_bf16.h>
#include <hip/hip_fp16.h>

// Problem: B=4, N=1024, C=1024, H=16, D=64.  epoch=25 -> band window w=8.
// Pipeline: convert->GEMM1(qkv)->banded attention->GEMM2(+bias).

typedef __bf16 bf16x8_t __attribute__((ext_vector_type(8)));
typedef float f32x4_t __attribute__((ext_vector_type(4)));

#define TILE 128
#define BK 32

__device__ __forceinline__ void load_lds16(const void* g, void* l) {
    __builtin_amdgcn_global_load_lds(
        (__attribute__((address_space(1))) void*)(g),
        (__attribute__((address_space(3))) void*)(l),
        16, 0, 0);
}

// ---------------- fp32 -> bf16 conversion (x, Wqkv, Wproj fused) -------------
// total elements: 4194304 + 3145728 + 1048576 = 8388608; 4 per thread.
__global__ __launch_bounds__(256) void convert_all(
    const float* __restrict__ x, const float* __restrict__ wqkv,
    const float* __restrict__ wproj,
    __hip_bfloat16* __restrict__ xb, __hip_bfloat16* __restrict__ wqkvb,
    __hip_bfloat16* __restrict__ wprojb)
{
    const size_t t = (size_t)blockIdx.x * 256 + threadIdx.x;
    size_t i = t * 4;
    const float* src;
    __hip_bfloat16* dst;
    if (i < 4194304) {
        src = x; dst = xb;
    } else if (i < 4194304 + 3145728) {
        src = wqkv; dst = wqkvb; i -= 4194304;
    } else {
        src = wproj; dst = wprojb; i -= 4194304 + 3145728;
    }
    float4 v = *reinterpret_cast<const float4*>(src + i);
    dst[i + 0] = __float2bfloat16(v.x);
    dst[i + 1] = __float2bfloat16(v.y);
    dst[i + 2] = __float2bfloat16(v.z);
    dst[i + 3] = __float2bfloat16(v.w);
}

// ---------------- bf16 GEMM, C[M,Nn] = A[M,K] * B[Nn,K]^T --------------------
// 128x128 tile, 4 waves (2x2 of 64x64), mfma_f32_16x16x32_bf16, BK=32.
template<bool BIAS_F32OUT>
__global__ __launch_bounds__(256) void gemm_bt(
    const __hip_bfloat16* __restrict__ A,
    const __hip_bfloat16* __restrict__ B,
    void* __restrict__ Cout,
    const float* __restrict__ bias,
    int M, int Nn, int K)
{
    __shared__ __hip_bfloat16 As[TILE * BK];  // 8 KB
    __shared__ __hip_bfloat16 Bs[TILE * BK];  // 8 KB

    const int tid  = threadIdx.x;
    const int m0   = blockIdx.y * TILE;
    const int n0   = blockIdx.x * TILE;
    const int wave = tid >> 6, lane = tid & 63;
    const int wr   = wave >> 1, wc = wave & 1;
    const int lr   = lane & 15, kg = lane >> 4;

    f32x4_t acc[4][4] = {};

    for (int k0 = 0; k0 < K; k0 += BK) {
        __syncthreads();
        // stage A and B tiles: 512 x 16B chunks each, 2 iterations of 256 thr
#pragma unroll
        for (int it = 0; it < 2; ++it) {
            const int c   = tid + it * 256;
            const int row = c >> 2;          // 0..127
            const int cb  = (c & 3) * 8;     // k element offset 0/8/16/24
            load_lds16(A + (size_t)(m0 + row) * K + k0 + cb,
                       (char*)As + (size_t)c * 16);
            load_lds16(B + (size_t)(n0 + row) * K + k0 + cb,
                       (char*)Bs + (size_t)c * 16);
        }
        __syncthreads();

        bf16x8_t a[4], b[4];
#pragma unroll
        for (int mi = 0; mi < 4; ++mi)
            a[mi] = *reinterpret_cast<const bf16x8_t*>(
                &As[(wr * 64 + mi * 16 + lr) * BK + kg * 8]);
#pragma unroll
        for (int ni = 0; ni < 4; ++ni)
            b[ni] = *reinterpret_cast<const bf16x8_t*>(
                &Bs[(wc * 64 + ni * 16 + lr) * BK + kg * 8]);
#pragma unroll
        for (int mi = 0; mi < 4; ++mi)
#pragma unroll
            for (int ni = 0; ni < 4; ++ni)
                acc[mi][ni] = __builtin_amdgcn_mfma_f32_16x16x32_bf16(
                    a[mi], b[ni], acc[mi][ni], 0, 0, 0);
    }

    // epilogue: D row = (lane>>4)*4 + r, col = lane&15  (measured layout)
    const int crow0 = kg * 4;
#pragma unroll
    for (int mi = 0; mi < 4; ++mi) {
#pragma unroll
        for (int ni = 0; ni < 4; ++ni) {
            const int col = n0 + wc * 64 + ni * 16 + lr;
#pragma unroll
            for (int r = 0; r < 4; ++r) {
                const int row = m0 + wr * 64 + mi * 16 + crow0 + r;
                const float v = acc[mi][ni][r];
                if (BIAS_F32OUT) {
                    ((float*)Cout)[(size_t)row * Nn + col] = v + bias[col];
                } else {
                    ((__hip_bfloat16*)Cout)[(size_t)row * Nn + col] =
                        __float2bfloat16(v);
                }
            }
        }
    }
}

// ---------------- banded attention ------------------------------------------
// qkv: [B*N, 3C] bf16, per-head interleaved: head h occupies cols h*192..h*192+191
// (q: +0..63, k: +64..127, v: +128..191).  One wave per (b,h,i) query row.
__global__ __launch_bounds__(256) void attn_band(
    const __hip_bfloat16* __restrict__ qkv,
    __hip_bfloat16* __restrict__ ctx,
    const int* __restrict__ epoch_ptr)
{
    const int wave = threadIdx.x >> 6, lane = threadIdx.x & 63;
    const int r  = blockIdx.x * 4 + wave;    // (b*H + h)*N + i
    const int i  = r & 1023;
    const int bh = r >> 10;
    const int h  = bh & 15;
    const int b  = bh >> 4;

    const int e = *epoch_ptr;
    int w;
    if      (e < 20) w = 6;
    else if (e < 30) w = 8;
    else if (e < 40) w = 10;
    else if (e < 50) w = 12;
    else             w = 1023;   // no mask

    const int hq = h * 192;
    float q = __bfloat162float(qkv[((size_t)b * 1024 + i) * 3072 + hq + lane]);
    q *= 0.125f;   // d^-0.5, folded into q

    const int jlo = i - w < 0 ? 0 : i - w;
    const int jhi = i + w > 1023 ? 1023 : i + w;

    float m = -1e30f, l = 0.f, acc = 0.f;
    for (int j = jlo; j <= jhi; ++j) {
        const __hip_bfloat16* kr =
            qkv + ((size_t)b * 1024 + j) * 3072 + hq + 64;
        float s = q * __bfloat162float(kr[lane]);
#pragma unroll
        for (int off = 32; off; off >>= 1) s += __shfl_xor(s, off);
        const float vd = __bfloat162float(kr[64 + lane]);
        const float mn = fmaxf(m, s);
        const float sc = __expf(m - mn);
        const float p  = __expf(s - mn);
        l   = l * sc + p;
        acc = acc * sc + p * vd;
        m = mn;
    }
    ctx[((size_t)b * 1024 + i) * 1024 + h * 64 + lane] =
        __float2bfloat16(acc / l);
}

// ---------------- launch -----------------------------------------------------
extern "C" void kernel_launch(void* const* d_in, const int* in_sizes, int n_in,
                              void* d_out, int out_size, void* d_ws, size_t ws_size,
                              hipStream_t stream)
{
    const float* x     = (const float*)d_in[0];   // [4,1024,1024]
    const float* Wqkv  = (const float*)d_in[1];   // [3072,1024]
    const float* Wproj = (const float*)d_in[2];   // [1024,1024]
    const float* bproj = (const float*)d_in[3];   // [1024]
    const int*   epoch = (const int*)d_in[4];     // scalar

    char* ws = (char*)d_ws;
    __hip_bfloat16* xb     = (__hip_bfloat16*)(ws);
    __hip_bfloat16* wqkvb  = (__hip_bfloat16*)(ws + 8388608);
    __hip_bfloat16* wprojb = (__hip_bfloat16*)(ws + 8388608 + 6291456);
    __hip_bfloat16* qkvb   = (__hip_bfloat16*)(ws + 16777216);
    __hip_bfloat16* ctxb   = (__hip_bfloat16*)(ws + 16777216 + 25165824);
    // total ws use: 50331648 bytes

    // 1. fp32 -> bf16
    convert_all<<<8192, 256, 0, stream>>>(x, Wqkv, Wproj, xb, wqkvb, wprojb);

    // 2. qkv = x @ Wqkv^T   [4096,3072] = [4096,1024] x [3072,1024]^T
    gemm_bt<false><<<dim3(3072 / TILE, 4096 / TILE), 256, 0, stream>>>(
        xb, wqkvb, qkvb, nullptr, 4096, 3072, 1024);

    // 3. banded attention -> ctx [4096,1024]
    attn_band<<<(4 * 16 * 1024) / 4, 256, 0, stream>>>(qkvb, ctxb, epoch);

    // 4. out = ctx @ Wproj^T + bproj  (fp32 out)
    gemm_bt<true><<<dim3(1024 / TILE, 4096 / TILE), 256, 0, stream>>>(
        ctxb, wprojb, d_out, bproj, 4096, 1024, 1024);
}

// Round 2
// 89.523 us; speedup vs baseline: 1.7803x; 1.7803x over previous
//
#include <hip/hip_runtime.h>
#include <hip/hip_bf16.h>

// Problem: B=4, N=1024, C=1024, H=16, D=64.  epoch=25 -> band window w=8.
// Pipeline: convert->GEMM1(qkv)->banded MFMA attention->GEMM2(+bias).

typedef __bf16 bf16x8_t __attribute__((ext_vector_type(8)));
typedef unsigned short u16x8_t __attribute__((ext_vector_type(8)));
typedef float f32x4_t __attribute__((ext_vector_type(4)));

#define TILE 128
#define BK 32

__device__ __forceinline__ void load_lds16(const void* g, void* l) {
    __builtin_amdgcn_global_load_lds(
        (__attribute__((address_space(1))) void*)(g),
        (__attribute__((address_space(3))) void*)(l),
        16, 0, 0);
}

// ---------------- fp32 -> bf16 conversion (x, Wqkv, Wproj fused) -------------
__global__ __launch_bounds__(256) void convert_all(
    const float* __restrict__ x, const float* __restrict__ wqkv,
    const float* __restrict__ wproj,
    __hip_bfloat16* __restrict__ xb, __hip_bfloat16* __restrict__ wqkvb,
    __hip_bfloat16* __restrict__ wprojb)
{
    const size_t t = (size_t)blockIdx.x * 256 + threadIdx.x;
    size_t i = t * 4;
    const float* src;
    __hip_bfloat16* dst;
    if (i < 4194304) {
        src = x; dst = xb;
    } else if (i < 4194304 + 3145728) {
        src = wqkv; dst = wqkvb; i -= 4194304;
    } else {
        src = wproj; dst = wprojb; i -= 4194304 + 3145728;
    }
    float4 v = *reinterpret_cast<const float4*>(src + i);
    dst[i + 0] = __float2bfloat16(v.x);
    dst[i + 1] = __float2bfloat16(v.y);
    dst[i + 2] = __float2bfloat16(v.z);
    dst[i + 3] = __float2bfloat16(v.w);
}

// ---------------- bf16 GEMM, C[M,Nn] = A[M,K] * B[Nn,K]^T --------------------
template<bool BIAS_F32OUT>
__global__ __launch_bounds__(256) void gemm_bt(
    const __hip_bfloat16* __restrict__ A,
    const __hip_bfloat16* __restrict__ B,
    void* __restrict__ Cout,
    const float* __restrict__ bias,
    int M, int Nn, int K)
{
    __shared__ __hip_bfloat16 As[TILE * BK];
    __shared__ __hip_bfloat16 Bs[TILE * BK];

    const int tid  = threadIdx.x;
    const int m0   = blockIdx.y * TILE;
    const int n0   = blockIdx.x * TILE;
    const int wave = tid >> 6, lane = tid & 63;
    const int wr   = wave >> 1, wc = wave & 1;
    const int lr   = lane & 15, kg = lane >> 4;

    f32x4_t acc[4][4] = {};

    for (int k0 = 0; k0 < K; k0 += BK) {
        __syncthreads();
#pragma unroll
        for (int it = 0; it < 2; ++it) {
            const int c   = tid + it * 256;
            const int row = c >> 2;
            const int cb  = (c & 3) * 8;
            load_lds16(A + (size_t)(m0 + row) * K + k0 + cb,
                       (char*)As + (size_t)c * 16);
            load_lds16(B + (size_t)(n0 + row) * K + k0 + cb,
                       (char*)Bs + (size_t)c * 16);
        }
        __syncthreads();

        bf16x8_t a[4], b[4];
#pragma unroll
        for (int mi = 0; mi < 4; ++mi)
            a[mi] = *reinterpret_cast<const bf16x8_t*>(
                &As[(wr * 64 + mi * 16 + lr) * BK + kg * 8]);
#pragma unroll
        for (int ni = 0; ni < 4; ++ni)
            b[ni] = *reinterpret_cast<const bf16x8_t*>(
                &Bs[(wc * 64 + ni * 16 + lr) * BK + kg * 8]);
#pragma unroll
        for (int mi = 0; mi < 4; ++mi)
#pragma unroll
            for (int ni = 0; ni < 4; ++ni)
                acc[mi][ni] = __builtin_amdgcn_mfma_f32_16x16x32_bf16(
                    a[mi], b[ni], acc[mi][ni], 0, 0, 0);
    }

    const int crow0 = kg * 4;
#pragma unroll
    for (int mi = 0; mi < 4; ++mi) {
#pragma unroll
        for (int ni = 0; ni < 4; ++ni) {
            const int col = n0 + wc * 64 + ni * 16 + lr;
#pragma unroll
            for (int r = 0; r < 4; ++r) {
                const int row = m0 + wr * 64 + mi * 16 + crow0 + r;
                const float v = acc[mi][ni][r];
                if (BIAS_F32OUT) {
                    ((float*)Cout)[(size_t)row * Nn + col] = v + bias[col];
                } else {
                    ((__hip_bfloat16*)Cout)[(size_t)row * Nn + col] =
                        __float2bfloat16(v);
                }
            }
        }
    }
}

// ---------------- banded MFMA attention --------------------------------------
// qkv: [4096, 3072] bf16, head h at cols h*192 (+0 q, +64 k, +128 v).
// One wave per 16-query tile; online softmax over aligned 32-key pair tiles.
// S layout (16x16x32 mfma C): row q = (lane>>4)*4+r, col key = lane&15.
// PV:   A-frag = P[q=lane&15][key=(lane>>4)*8+e] from LDS,
//       B-frag = V^T[d=lane&15+16ni][key] from LDS (reg-transposed staging).
__global__ __launch_bounds__(256) void attn_band_mfma(
    const __hip_bfloat16* __restrict__ qkv,
    __hip_bfloat16* __restrict__ ctx,
    const int* __restrict__ epoch_ptr)
{
    // 80 B row stride: b128-aligned, odd 16B-multiple -> low bank conflicts
    __shared__ __hip_bfloat16 P_lds[4][16 * 40];
    __shared__ __hip_bfloat16 V_lds[4][64 * 40];

    const int wave = threadIdx.x >> 6;
    const int lane = threadIdx.x & 63;
    const int lr = lane & 15, kg = lane >> 4;

    const int bid = blockIdx.x;           // ((b*16 + h)*16 + tg)
    const int tg = bid & 15;
    const int bh = bid >> 4;
    const int h = bh & 15, b = bh >> 4;
    const int i0 = (tg * 4 + wave) * 16;  // query tile base

    const int e = *epoch_ptr;
    int w;
    if      (e < 20) w = 6;
    else if (e < 30) w = 8;
    else if (e < 40) w = 10;
    else if (e < 50) w = 12;
    else             w = 1023;            // no mask -> full attention

    const size_t rowb = (size_t)b * 1024;
    const int hq = h * 192;

    // Q fragments: A(m=q=lr, k=dim kg*8+e + 32*ks)
    bf16x8_t aq[2];
#pragma unroll
    for (int ks = 0; ks < 2; ++ks)
        aq[ks] = *(const bf16x8_t*)(qkv + (rowb + i0 + lr) * 3072 + hq + ks * 32 + kg * 8);

    float m[4] = {-1e30f, -1e30f, -1e30f, -1e30f};
    float l[4] = {0.f, 0.f, 0.f, 0.f};
    f32x4_t o[4] = {};

    int jlo = i0 - w;      if (jlo < 0) jlo = 0;
    int jhi = i0 + 15 + w; if (jhi > 1023) jhi = 1023;

    for (int p = (jlo >> 5); p <= (jhi >> 5); ++p) {
        const int kb = p * 32;

        // ---- V loads (issue early; lane owns keys kb+2*lr, +1; dims kg*16..+15)
        const __hip_bfloat16* vbase0 = qkv + (rowb + kb + 2 * lr) * 3072 + hq + 128 + kg * 16;
        const __hip_bfloat16* vbase1 = vbase0 + 3072;
        u16x8_t va0 = *(const u16x8_t*)(vbase0);
        u16x8_t vb0 = *(const u16x8_t*)(vbase0 + 8);
        u16x8_t va1 = *(const u16x8_t*)(vbase1);
        u16x8_t vb1 = *(const u16x8_t*)(vbase1 + 8);

        // ---- S = Q K^T over two 16-key subtiles, K-dim = 64 (2 ksteps)
        f32x4_t s[2] = {};
#pragma unroll
        for (int t = 0; t < 2; ++t)
#pragma unroll
            for (int ks = 0; ks < 2; ++ks) {
                bf16x8_t bk = *(const bf16x8_t*)(
                    qkv + (rowb + kb + t * 16 + lr) * 3072 + hq + 64 + ks * 32 + kg * 8);
                s[t] = __builtin_amdgcn_mfma_f32_16x16x32_bf16(aq[ks], bk, s[t], 0, 0, 0);
            }

        // ---- V^T -> LDS: V_lds[d][key-kb], packed 2 keys per b32 write
#pragma unroll
        for (int c = 0; c < 8; ++c) {
            unsigned int pk = (unsigned int)va0[c] | ((unsigned int)va1[c] << 16);
            *(unsigned int*)&V_lds[wave][(kg * 16 + c) * 40 + 2 * lr] = pk;
        }
#pragma unroll
        for (int c = 0; c < 8; ++c) {
            unsigned int pk = (unsigned int)vb0[c] | ((unsigned int)vb1[c] << 16);
            *(unsigned int*)&V_lds[wave][(kg * 16 + 8 + c) * 40 + 2 * lr] = pk;
        }

        // ---- scale + band mask
        float sv[2][4];
#pragma unroll
        for (int t = 0; t < 2; ++t)
#pragma unroll
            for (int r = 0; r < 4; ++r) {
                const int qi = i0 + kg * 4 + r;
                const int j  = kb + t * 16 + lr;
                int d = qi - j; if (d < 0) d = -d;
                sv[t][r] = (d <= w) ? s[t][r] * 0.125f : -1e30f;
            }

        // ---- row max across the 16 key lanes (4 independent chains)
        float tm[4];
#pragma unroll
        for (int r = 0; r < 4; ++r) tm[r] = fmaxf(sv[0][r], sv[1][r]);
#pragma unroll
        for (int msk = 1; msk < 16; msk <<= 1)
#pragma unroll
            for (int r = 0; r < 4; ++r) tm[r] = fmaxf(tm[r], __shfl_xor(tm[r], msk));

        // ---- online softmax update
        float sc[4], ps[4], pvv[2][4];
#pragma unroll
        for (int r = 0; r < 4; ++r) {
            const float mn = fmaxf(m[r], tm[r]);
            sc[r] = __expf(m[r] - mn);
            pvv[0][r] = __expf(sv[0][r] - mn);
            pvv[1][r] = __expf(sv[1][r] - mn);
            ps[r] = pvv[0][r] + pvv[1][r];
            m[r] = mn;
        }
#pragma unroll
        for (int msk = 1; msk < 16; msk <<= 1)
#pragma unroll
            for (int r = 0; r < 4; ++r) ps[r] += __shfl_xor(ps[r], msk);
#pragma unroll
        for (int r = 0; r < 4; ++r) l[r] = l[r] * sc[r] + ps[r];
#pragma unroll
        for (int ni = 0; ni < 4; ++ni)
#pragma unroll
            for (int r = 0; r < 4; ++r) o[ni][r] *= sc[r];

        // ---- P -> LDS (bf16)
#pragma unroll
        for (int t = 0; t < 2; ++t)
#pragma unroll
            for (int r = 0; r < 4; ++r)
                P_lds[wave][(kg * 4 + r) * 40 + t * 16 + lr] =
                    __float2bfloat16(pvv[t][r]);

        // ---- PV: o[ni] += P[16x32] * V[32x(16ni..)]
        bf16x8_t ap = *(const bf16x8_t*)&P_lds[wave][lr * 40 + kg * 8];
#pragma unroll
        for (int ni = 0; ni < 4; ++ni) {
            bf16x8_t bv = *(const bf16x8_t*)&V_lds[wave][(ni * 16 + lr) * 40 + kg * 8];
            o[ni] = __builtin_amdgcn_mfma_f32_16x16x32_bf16(ap, bv, o[ni], 0, 0, 0);
        }
    }

    // ---- epilogue: ctx[b*1024+i][h*64+d]
#pragma unroll
    for (int ni = 0; ni < 4; ++ni)
#pragma unroll
        for (int r = 0; r < 4; ++r)
            ctx[(rowb + i0 + kg * 4 + r) * 1024 + h * 64 + ni * 16 + lr] =
                __float2bfloat16(o[ni][r] / l[r]);
}

// ---------------- launch -----------------------------------------------------
extern "C" void kernel_launch(void* const* d_in, const int* in_sizes, int n_in,
                              void* d_out, int out_size, void* d_ws, size_t ws_size,
                              hipStream_t stream)
{
    const float* x     = (const float*)d_in[0];
    const float* Wqkv  = (const float*)d_in[1];
    const float* Wproj = (const float*)d_in[2];
    const float* bproj = (const float*)d_in[3];
    const int*   epoch = (const int*)d_in[4];

    char* ws = (char*)d_ws;
    __hip_bfloat16* xb     = (__hip_bfloat16*)(ws);
    __hip_bfloat16* wqkvb  = (__hip_bfloat16*)(ws + 8388608);
    __hip_bfloat16* wprojb = (__hip_bfloat16*)(ws + 8388608 + 6291456);
    __hip_bfloat16* qkvb   = (__hip_bfloat16*)(ws + 16777216);
    __hip_bfloat16* ctxb   = (__hip_bfloat16*)(ws + 16777216 + 25165824);

    convert_all<<<8192, 256, 0, stream>>>(x, Wqkv, Wproj, xb, wqkvb, wprojb);

    gemm_bt<false><<<dim3(3072 / TILE, 4096 / TILE), 256, 0, stream>>>(
        xb, wqkvb, qkvb, nullptr, 4096, 3072, 1024);

    attn_band_mfma<<<1024, 256, 0, stream>>>(qkvb, ctxb, epoch);

    gemm_bt<true><<<dim3(1024 / TILE, 4096 / TILE), 256, 0, stream>>>(
        ctxb, wprojb, d_out, bproj, 4096, 1024, 1024);
}

// Round 4
// 81.235 us; speedup vs baseline: 1.9620x; 1.1020x over previous
//
#include <hip/hip_runtime.h>
#include <hip/hip_bf16.h>

// Problem: B=4, N=1024, C=1024, H=16, D=64.  epoch=25 -> band window w=8.
// Pipeline: convert->GEMM1(qkv)->banded MFMA attention->GEMM2(+bias).

typedef __bf16 bf16x8_t __attribute__((ext_vector_type(8)));
typedef unsigned short u16x8_t __attribute__((ext_vector_type(8)));
typedef float f32x4_t __attribute__((ext_vector_type(4)));

__device__ __forceinline__ void load_lds16(const void* g, void* l) {
    __builtin_amdgcn_global_load_lds(
        (__attribute__((address_space(1))) void*)(g),
        (__attribute__((address_space(3))) void*)(l),
        16, 0, 0);
}

// ---------------- fp32 -> bf16 conversion (x, Wqkv, Wproj fused) -------------
// 8388608 elements, 8 per thread, 16B packed stores.
__global__ __launch_bounds__(256) void convert_all(
    const float* __restrict__ x, const float* __restrict__ wqkv,
    const float* __restrict__ wproj,
    __hip_bfloat16* __restrict__ xb, __hip_bfloat16* __restrict__ wqkvb,
    __hip_bfloat16* __restrict__ wprojb)
{
    const size_t t = (size_t)blockIdx.x * 256 + threadIdx.x;
    size_t i = t * 8;
    const float* src;
    __hip_bfloat16* dst;
    if (i < 4194304) {
        src = x; dst = xb;
    } else if (i < 4194304 + 3145728) {
        src = wqkv; dst = wqkvb; i -= 4194304;
    } else {
        src = wproj; dst = wprojb; i -= 4194304 + 3145728;
    }
    float4 v0 = *reinterpret_cast<const float4*>(src + i);
    float4 v1 = *reinterpret_cast<const float4*>(src + i + 4);
    union { u16x8_t v; __hip_bfloat16 h[8]; } u;
    u.h[0] = __float2bfloat16(v0.x); u.h[1] = __float2bfloat16(v0.y);
    u.h[2] = __float2bfloat16(v0.z); u.h[3] = __float2bfloat16(v0.w);
    u.h[4] = __float2bfloat16(v1.x); u.h[5] = __float2bfloat16(v1.y);
    u.h[6] = __float2bfloat16(v1.z); u.h[7] = __float2bfloat16(v1.w);
    *reinterpret_cast<u16x8_t*>(dst + i) = u.v;
}

// ---------------- GEMM1: qkv = xb @ WqkvT, bf16 out --------------------------
// 128x128 tile, 4 waves (2x2 of 64x64), BK=32, coalesced LDS-staged epilogue.
__global__ __launch_bounds__(256) void gemm1_qkv(
    const __hip_bfloat16* __restrict__ A,   // [4096,1024]
    const __hip_bfloat16* __restrict__ B,   // [3072,1024]
    __hip_bfloat16* __restrict__ C)         // [4096,3072]
{
    __shared__ char smem[16384];            // stage: As@0 (8KB), Bs@8192 (8KB)
    const int tid = threadIdx.x;
    const int m0 = blockIdx.y * 128, n0 = blockIdx.x * 128;
    const int wave = tid >> 6, lane = tid & 63;
    const int wr = wave >> 1, wc = wave & 1;
    const int lr = lane & 15, kg = lane >> 4;
    const int K = 1024, Nn = 3072;

    f32x4_t acc[4][4] = {};

    for (int k0 = 0; k0 < K; k0 += 32) {
        __syncthreads();
#pragma unroll
        for (int it = 0; it < 2; ++it) {
            const int c = tid + it * 256;
            const int row = c >> 2, cb = (c & 3) * 8;
            load_lds16(A + (size_t)(m0 + row) * K + k0 + cb, smem + c * 16);
            load_lds16(B + (size_t)(n0 + row) * K + k0 + cb,
                       smem + 8192 + c * 16);
        }
        __syncthreads();

        bf16x8_t a[4], b[4];
#pragma unroll
        for (int mi = 0; mi < 4; ++mi)
            a[mi] = *reinterpret_cast<const bf16x8_t*>(
                smem + ((wr * 64 + mi * 16 + lr) * 32 + kg * 8) * 2);
#pragma unroll
        for (int ni = 0; ni < 4; ++ni)
            b[ni] = *reinterpret_cast<const bf16x8_t*>(
                smem + 8192 + ((wc * 64 + ni * 16 + lr) * 32 + kg * 8) * 2);
#pragma unroll
        for (int mi = 0; mi < 4; ++mi)
#pragma unroll
            for (int ni = 0; ni < 4; ++ni)
                acc[mi][ni] = __builtin_amdgcn_mfma_f32_16x16x32_bf16(
                    a[mi], b[ni], acc[mi][ni], 0, 0, 0);
    }

    // epilogue: 2 passes of 64 rows through LDS, dwordx4 global stores
    __syncthreads();
#pragma unroll
    for (int p = 0; p < 2; ++p) {
        if (p) __syncthreads();
        if (wr == p) {
#pragma unroll
            for (int mi = 0; mi < 4; ++mi)
#pragma unroll
                for (int ni = 0; ni < 4; ++ni) {
                    const int scol = wc * 64 + ni * 16 + lr;
#pragma unroll
                    for (int r = 0; r < 4; ++r) {
                        const int srow = mi * 16 + kg * 4 + r;
                        ((__hip_bfloat16*)smem)[srow * 128 + scol] =
                            __float2bfloat16(acc[mi][ni][r]);
                    }
                }
        }
        __syncthreads();
#pragma unroll
        for (int cc = 0; cc < 4; ++cc) {
            const int chunk = tid + cc * 256;   // 1024 x 16B = [64][128] bf16
            const int srow = chunk >> 4;
            const int sc16 = chunk & 15;
            f32x4_t v = *reinterpret_cast<const f32x4_t*>(smem + chunk * 16);
            *reinterpret_cast<f32x4_t*>(
                (char*)C + ((size_t)(m0 + p * 64 + srow) * Nn + n0) * 2 +
                sc16 * 16) = v;
        }
    }
}

// ---------------- GEMM2: out = ctx @ WprojT + bias, fp32 out -----------------
// 64x128 tile (512 blocks = 2/CU), 4 waves (2x2 of 32x64), BK=32.
__global__ __launch_bounds__(256) void gemm2_proj(
    const __hip_bfloat16* __restrict__ A,   // ctx [4096,1024]
    const __hip_bfloat16* __restrict__ B,   // Wproj [1024,1024]
    float* __restrict__ C,                  // [4096,1024]
    const float* __restrict__ bias)
{
    __shared__ char smem[16384];            // stage: As@0 (4KB), Bs@4096 (8KB)
    const int tid = threadIdx.x;
    const int m0 = blockIdx.y * 64, n0 = blockIdx.x * 128;
    const int wave = tid >> 6, lane = tid & 63;
    const int wr = wave >> 1, wc = wave & 1;
    const int lr = lane & 15, kg = lane >> 4;
    const int K = 1024, Nn = 1024;

    f32x4_t acc[2][4] = {};

    for (int k0 = 0; k0 < K; k0 += 32) {
        __syncthreads();
        {
            const int row = tid >> 2, cb = (tid & 3) * 8;
            load_lds16(A + (size_t)(m0 + row) * K + k0 + cb, smem + tid * 16);
        }
#pragma unroll
        for (int it = 0; it < 2; ++it) {
            const int c = tid + it * 256;
            const int row = c >> 2, cb = (c & 3) * 8;
            load_lds16(B + (size_t)(n0 + row) * K + k0 + cb,
                       smem + 4096 + c * 16);
        }
        __syncthreads();

        bf16x8_t a[2], b[4];
#pragma unroll
        for (int mi = 0; mi < 2; ++mi)
            a[mi] = *reinterpret_cast<const bf16x8_t*>(
                smem + ((wr * 32 + mi * 16 + lr) * 32 + kg * 8) * 2);
#pragma unroll
        for (int ni = 0; ni < 4; ++ni)
            b[ni] = *reinterpret_cast<const bf16x8_t*>(
                smem + 4096 + ((wc * 64 + ni * 16 + lr) * 32 + kg * 8) * 2);
#pragma unroll
        for (int mi = 0; mi < 2; ++mi)
#pragma unroll
            for (int ni = 0; ni < 4; ++ni)
                acc[mi][ni] = __builtin_amdgcn_mfma_f32_16x16x32_bf16(
                    a[mi], b[ni], acc[mi][ni], 0, 0, 0);
    }

    // epilogue: 2 passes of 32 rows (fp32) through LDS, bias in copy phase
    __syncthreads();
#pragma unroll
    for (int p = 0; p < 2; ++p) {
        if (p) __syncthreads();
        if (wr == p) {
#pragma unroll
            for (int mi = 0; mi < 2; ++mi)
#pragma unroll
                for (int ni = 0; ni < 4; ++ni) {
                    const int scol = wc * 64 + ni * 16 + lr;
#pragma unroll
                    for (int r = 0; r < 4; ++r) {
                        const int srow = mi * 16 + kg * 4 + r;
                        ((float*)smem)[srow * 128 + scol] = acc[mi][ni][r];
                    }
                }
        }
        __syncthreads();
#pragma unroll
        for (int cc = 0; cc < 4; ++cc) {
            const int chunk = tid + cc * 256;   // 1024 x 16B = [32][128] f32
            const int srow = chunk >> 5;
            const int sc = (chunk & 31) * 4;
            f32x4_t v = *reinterpret_cast<const f32x4_t*>(smem + chunk * 16);
            const f32x4_t bv = *reinterpret_cast<const f32x4_t*>(bias + n0 + sc);
            v += bv;
            *reinterpret_cast<f32x4_t*>(
                C + (size_t)(m0 + p * 32 + srow) * Nn + n0 + sc) = v;
        }
    }
}

// ---------------- banded MFMA attention --------------------------------------
__global__ __launch_bounds__(256) void attn_band_mfma(
    const __hip_bfloat16* __restrict__ qkv,
    __hip_bfloat16* __restrict__ ctx,
    const int* __restrict__ epoch_ptr)
{
    __shared__ __hip_bfloat16 P_lds[4][16 * 40];
    __shared__ __hip_bfloat16 V_lds[4][64 * 40];

    const int wave = threadIdx.x >> 6;
    const int lane = threadIdx.x & 63;
    const int lr = lane & 15, kg = lane >> 4;

    const int bid = blockIdx.x;
    const int tg = bid & 15;
    const int bh = bid >> 4;
    const int h = bh & 15, b = bh >> 4;
    const int i0 = (tg * 4 + wave) * 16;

    const int e = *epoch_ptr;
    int w;
    if      (e < 20) w = 6;
    else if (e < 30) w = 8;
    else if (e < 40) w = 10;
    else if (e < 50) w = 12;
    else             w = 1023;

    const size_t rowb = (size_t)b * 1024;
    const int hq = h * 192;

    bf16x8_t aq[2];
#pragma unroll
    for (int ks = 0; ks < 2; ++ks)
        aq[ks] = *(const bf16x8_t*)(qkv + (rowb + i0 + lr) * 3072 + hq + ks * 32 + kg * 8);

    float m[4] = {-1e30f, -1e30f, -1e30f, -1e30f};
    float l[4] = {0.f, 0.f, 0.f, 0.f};
    f32x4_t o[4] = {};

    int jlo = i0 - w;      if (jlo < 0) jlo = 0;
    int jhi = i0 + 15 + w; if (jhi > 1023) jhi = 1023;

    for (int p = (jlo >> 5); p <= (jhi >> 5); ++p) {
        const int kb = p * 32;

        const __hip_bfloat16* vbase0 = qkv + (rowb + kb + 2 * lr) * 3072 + hq + 128 + kg * 16;
        const __hip_bfloat16* vbase1 = vbase0 + 3072;
        u16x8_t va0 = *(const u16x8_t*)(vbase0);
        u16x8_t vb0 = *(const u16x8_t*)(vbase0 + 8);
        u16x8_t va1 = *(const u16x8_t*)(vbase1);
        u16x8_t vb1 = *(const u16x8_t*)(vbase1 + 8);

        f32x4_t s[2] = {};
#pragma unroll
        for (int t = 0; t < 2; ++t)
#pragma unroll
            for (int ks = 0; ks < 2; ++ks) {
                bf16x8_t bk = *(const bf16x8_t*)(
                    qkv + (rowb + kb + t * 16 + lr) * 3072 + hq + 64 + ks * 32 + kg * 8);
                s[t] = __builtin_amdgcn_mfma_f32_16x16x32_bf16(aq[ks], bk, s[t], 0, 0, 0);
            }

#pragma unroll
        for (int c = 0; c < 8; ++c) {
            unsigned int pk = (unsigned int)va0[c] | ((unsigned int)va1[c] << 16);
            *(unsigned int*)&V_lds[wave][(kg * 16 + c) * 40 + 2 * lr] = pk;
        }
#pragma unroll
        for (int c = 0; c < 8; ++c) {
            unsigned int pk = (unsigned int)vb0[c] | ((unsigned int)vb1[c] << 16);
            *(unsigned int*)&V_lds[wave][(kg * 16 + 8 + c) * 40 + 2 * lr] = pk;
        }

        float sv[2][4];
#pragma unroll
        for (int t = 0; t < 2; ++t)
#pragma unroll
            for (int r = 0; r < 4; ++r) {
                const int qi = i0 + kg * 4 + r;
                const int j  = kb + t * 16 + lr;
                int d = qi - j; if (d < 0) d = -d;
                sv[t][r] = (d <= w) ? s[t][r] * 0.125f : -1e30f;
            }

        float tm[4];
#pragma unroll
        for (int r = 0; r < 4; ++r) tm[r] = fmaxf(sv[0][r], sv[1][r]);
#pragma unroll
        for (int msk = 1; msk < 16; msk <<= 1)
#pragma unroll
            for (int r = 0; r < 4; ++r) tm[r] = fmaxf(tm[r], __shfl_xor(tm[r], msk));

        float sc[4], ps[4], pvv[2][4];
#pragma unroll
        for (int r = 0; r < 4; ++r) {
            const float mn = fmaxf(m[r], tm[r]);
            sc[r] = __expf(m[r] - mn);
            pvv[0][r] = __expf(sv[0][r] - mn);
            pvv[1][r] = __expf(sv[1][r] - mn);
            ps[r] = pvv[0][r] + pvv[1][r];
            m[r] = mn;
        }
#pragma unroll
        for (int msk = 1; msk < 16; msk <<= 1)
#pragma unroll
            for (int r = 0; r < 4; ++r) ps[r] += __shfl_xor(ps[r], msk);
#pragma unroll
        for (int r = 0; r < 4; ++r) l[r] = l[r] * sc[r] + ps[r];
#pragma unroll
        for (int ni = 0; ni < 4; ++ni)
#pragma unroll
            for (int r = 0; r < 4; ++r) o[ni][r] *= sc[r];

#pragma unroll
        for (int t = 0; t < 2; ++t)
#pragma unroll
            for (int r = 0; r < 4; ++r)
                P_lds[wave][(kg * 4 + r) * 40 + t * 16 + lr] =
                    __float2bfloat16(pvv[t][r]);

        bf16x8_t ap = *(const bf16x8_t*)&P_lds[wave][lr * 40 + kg * 8];
#pragma unroll
        for (int ni = 0; ni < 4; ++ni) {
            bf16x8_t bv = *(const bf16x8_t*)&V_lds[wave][(ni * 16 + lr) * 40 + kg * 8];
            o[ni] = __builtin_amdgcn_mfma_f32_16x16x32_bf16(ap, bv, o[ni], 0, 0, 0);
        }
    }

#pragma unroll
    for (int ni = 0; ni < 4; ++ni)
#pragma unroll
        for (int r = 0; r < 4; ++r)
            ctx[(rowb + i0 + kg * 4 + r) * 1024 + h * 64 + ni * 16 + lr] =
                __float2bfloat16(o[ni][r] / l[r]);
}

// ---------------- launch -----------------------------------------------------
extern "C" void kernel_launch(void* const* d_in, const int* in_sizes, int n_in,
                              void* d_out, int out_size, void* d_ws, size_t ws_size,
                              hipStream_t stream)
{
    const float* x     = (const float*)d_in[0];
    const float* Wqkv  = (const float*)d_in[1];
    const float* Wproj = (const float*)d_in[2];
    const float* bproj = (const float*)d_in[3];
    const int*   epoch = (const int*)d_in[4];

    char* ws = (char*)d_ws;
    __hip_bfloat16* xb     = (__hip_bfloat16*)(ws);
    __hip_bfloat16* wqkvb  = (__hip_bfloat16*)(ws + 8388608);
    __hip_bfloat16* wprojb = (__hip_bfloat16*)(ws + 8388608 + 6291456);
    __hip_bfloat16* qkvb   = (__hip_bfloat16*)(ws + 16777216);
    __hip_bfloat16* ctxb   = (__hip_bfloat16*)(ws + 16777216 + 25165824);

    convert_all<<<4096, 256, 0, stream>>>(x, Wqkv, Wproj, xb, wqkvb, wprojb);

    gemm1_qkv<<<dim3(3072 / 128, 4096 / 128), 256, 0, stream>>>(xb, wqkvb, qkvb);

    attn_band_mfma<<<1024, 256, 0, stream>>>(qkvb, ctxb, epoch);

    gemm2_proj<<<dim3(1024 / 128, 4096 / 64), 256, 0, stream>>>(
        ctxb, wprojb, (float*)d_out, bproj);
}

// Round 5
// 78.552 us; speedup vs baseline: 2.0290x; 1.0342x over previous
//
#include <hip/hip_runtime.h>
#include <hip/hip_bf16.h>

// Problem: B=4, N=1024, C=1024, H=16, D=64.  epoch=25 -> band window w=8.
// Pipeline: convert->GEMM1(qkv, 256^2 deep-pipelined)->banded MFMA attention->GEMM2(+bias).

typedef __bf16 bf16x8_t __attribute__((ext_vector_type(8)));
typedef unsigned short u16x8_t __attribute__((ext_vector_type(8)));
typedef float f32x4_t __attribute__((ext_vector_type(4)));

__device__ __forceinline__ void load_lds16(const void* g, void* l) {
    __builtin_amdgcn_global_load_lds(
        (__attribute__((address_space(1))) void*)(g),
        (__attribute__((address_space(3))) void*)(l),
        16, 0, 0);
}

// ---------------- fp32 -> bf16 conversion (x, Wqkv, Wproj fused) -------------
__global__ __launch_bounds__(256) void convert_all(
    const float* __restrict__ x, const float* __restrict__ wqkv,
    const float* __restrict__ wproj,
    __hip_bfloat16* __restrict__ xb, __hip_bfloat16* __restrict__ wqkvb,
    __hip_bfloat16* __restrict__ wprojb)
{
    const size_t t = (size_t)blockIdx.x * 256 + threadIdx.x;
    size_t i = t * 8;
    const float* src;
    __hip_bfloat16* dst;
    if (i < 4194304) {
        src = x; dst = xb;
    } else if (i < 4194304 + 3145728) {
        src = wqkv; dst = wqkvb; i -= 4194304;
    } else {
        src = wproj; dst = wprojb; i -= 4194304 + 3145728;
    }
    float4 v0 = *reinterpret_cast<const float4*>(src + i);
    float4 v1 = *reinterpret_cast<const float4*>(src + i + 4);
    union { u16x8_t v; __hip_bfloat16 h[8]; } u;
    u.h[0] = __float2bfloat16(v0.x); u.h[1] = __float2bfloat16(v0.y);
    u.h[2] = __float2bfloat16(v0.z); u.h[3] = __float2bfloat16(v0.w);
    u.h[4] = __float2bfloat16(v1.x); u.h[5] = __float2bfloat16(v1.y);
    u.h[6] = __float2bfloat16(v1.z); u.h[7] = __float2bfloat16(v1.w);
    *reinterpret_cast<u16x8_t*>(dst + i) = u.v;
}

// ---------------- GEMM1: qkv = xb @ WqkvT, bf16 out --------------------------
// 256x256 tile, 512 thr = 8 waves (2M x 4N, 128x64 each), BK=32.
// 4-slot LDS rotation (slot = t&3): stage tile t+2 while computing tile t.
// Counted vmcnt(8) = 2 tiles in flight; ONE barrier per K-tile (no drain).
// LDS chunk swizzle: 16B-chunk ^= ((row>>1)&3), applied at staging source
// and ds_read address (involution) -> conflict-free fragment reads.
__global__ __launch_bounds__(512, 2) void gemm1_qkv256(
    const __hip_bfloat16* __restrict__ A,   // [4096,1024]
    const __hip_bfloat16* __restrict__ B,   // [3072,1024]
    __hip_bfloat16* __restrict__ C)         // [4096,3072]
{
    __shared__ __align__(16) char smem[135168];  // 4x32KB staging; 256x264 bf16 epilogue
    const int tid = threadIdx.x;
    const int m0 = blockIdx.y * 256, n0 = blockIdx.x * 256;
    const int wave = tid >> 6, lane = tid & 63;
    const int wr = wave >> 2, wc = wave & 3;       // 2M x 4N wave grid
    const int lr = lane & 15, kg = lane >> 4;
    const int K = 1024, Nn = 3072;

    // staging: A/B tile = 256 rows x 32 cols bf16 = 16KB = 1024 chunks of 16B.
    // thread stages chunks q0=tid, q1=tid+512 of each (lane-linear dest).
    // dest chunk (row=q>>2, slot=q&3) sources global col-chunk slot^((row>>1)&3).
    const int q0 = tid, q1 = tid + 512;
    const int ar0 = q0 >> 2, as0 = ((q0 & 3) ^ ((ar0 >> 1) & 3)) * 16;
    const int ar1 = q1 >> 2, as1 = ((q1 & 3) ^ ((ar1 >> 1) & 3)) * 16;
    const char* Asrc0 = (const char*)(A + (size_t)(m0 + ar0) * K) + as0;
    const char* Asrc1 = (const char*)(A + (size_t)(m0 + ar1) * K) + as1;
    const char* Bsrc0 = (const char*)(B + (size_t)(n0 + ar0) * K) + as0;
    const char* Bsrc1 = (const char*)(B + (size_t)(n0 + ar1) * K) + as1;

#define STAGE1(t) { const int sb_ = ((t) & 3) * 32768; const int ko_ = (t) * 64; \
    load_lds16(Asrc0 + ko_, smem + sb_ + q0 * 16);                               \
    load_lds16(Asrc1 + ko_, smem + sb_ + q1 * 16);                               \
    load_lds16(Bsrc0 + ko_, smem + sb_ + 16384 + q0 * 16);                       \
    load_lds16(Bsrc1 + ko_, smem + sb_ + 16384 + q1 * 16); }

    f32x4_t acc[8][4] = {};
    // swizzled read chunk offset within a 64B row: (kg ^ ((lr>>1)&3))*16
    const int rsw = ((kg ^ ((lr >> 1) & 3)) * 16);
    const int arow = wr * 128 + lr;      // A fragment row base (per mi: +16)
    const int brow = wc * 64 + lr;       // B fragment row base (per ni: +16)

#define COMPUTE1(t) { const int sb_ = ((t) & 3) * 32768;                          \
    bf16x8_t a_[8], b_[4];                                                        \
    _Pragma("unroll") for (int mi = 0; mi < 8; ++mi)                              \
        a_[mi] = *(const bf16x8_t*)(smem + sb_ + (arow + mi * 16) * 64 + rsw);    \
    _Pragma("unroll") for (int ni = 0; ni < 4; ++ni)                              \
        b_[ni] = *(const bf16x8_t*)(smem + sb_ + 16384 + (brow + ni * 16) * 64 + rsw); \
    __builtin_amdgcn_s_setprio(1);                                                \
    _Pragma("unroll") for (int mi = 0; mi < 8; ++mi)                              \
    _Pragma("unroll") for (int ni = 0; ni < 4; ++ni)                              \
        acc[mi][ni] = __builtin_amdgcn_mfma_f32_16x16x32_bf16(                    \
            a_[mi], b_[ni], acc[mi][ni], 0, 0, 0);                                \
    __builtin_amdgcn_s_setprio(0); }

    STAGE1(0);
    STAGE1(1);
    for (int t = 0; t < 30; ++t) {
        STAGE1(t + 2);                    // 12 loads outstanding
        asm volatile("s_waitcnt vmcnt(8)" ::: "memory");   // tile t landed
        __builtin_amdgcn_s_barrier();
        COMPUTE1(t);
    }
    asm volatile("s_waitcnt vmcnt(4)" ::: "memory");
    __builtin_amdgcn_s_barrier();
    COMPUTE1(30);
    asm volatile("s_waitcnt vmcnt(0)" ::: "memory");
    __builtin_amdgcn_s_barrier();
    COMPUTE1(31);
#undef STAGE1
#undef COMPUTE1

    // epilogue: C tile via LDS [256][264] bf16 (264: pad -> row stride 16 banks)
    __syncthreads();
    __hip_bfloat16* cl = (__hip_bfloat16*)smem;
#pragma unroll
    for (int mi = 0; mi < 8; ++mi)
#pragma unroll
        for (int ni = 0; ni < 4; ++ni)
#pragma unroll
            for (int r = 0; r < 4; ++r)
                cl[(wr * 128 + mi * 16 + kg * 4 + r) * 264 + wc * 64 + ni * 16 + lr] =
                    __float2bfloat16(acc[mi][ni][r]);
    __syncthreads();
#pragma unroll
    for (int c = 0; c < 16; ++c) {
        const int chunk = tid + c * 512;          // 8192 chunks = [256 rows][32 x 16B]
        const int row = chunk >> 5, cc = chunk & 31;
        f32x4_t v = *(const f32x4_t*)(smem + row * 528 + cc * 16);
        *(f32x4_t*)((char*)C + ((size_t)(m0 + row) * Nn + n0) * 2 + cc * 16) = v;
    }
}

// ---------------- GEMM2: out = ctx @ WprojT + bias, fp32 out -----------------
// 64x128 tile (512 blocks = 2/CU), 4 waves (2x2 of 32x64), BK=32.
__global__ __launch_bounds__(256) void gemm2_proj(
    const __hip_bfloat16* __restrict__ A,   // ctx [4096,1024]
    const __hip_bfloat16* __restrict__ B,   // Wproj [1024,1024]
    float* __restrict__ C,                  // [4096,1024]
    const float* __restrict__ bias)
{
    __shared__ char smem[16384];            // stage: As@0 (4KB), Bs@4096 (8KB)
    const int tid = threadIdx.x;
    const int m0 = blockIdx.y * 64, n0 = blockIdx.x * 128;
    const int wave = tid >> 6, lane = tid & 63;
    const int wr = wave >> 1, wc = wave & 1;
    const int lr = lane & 15, kg = lane >> 4;
    const int K = 1024, Nn = 1024;

    f32x4_t acc[2][4] = {};

    for (int k0 = 0; k0 < K; k0 += 32) {
        __syncthreads();
        {
            const int row = tid >> 2, cb = (tid & 3) * 8;
            load_lds16(A + (size_t)(m0 + row) * K + k0 + cb, smem + tid * 16);
        }
#pragma unroll
        for (int it = 0; it < 2; ++it) {
            const int c = tid + it * 256;
            const int row = c >> 2, cb = (c & 3) * 8;
            load_lds16(B + (size_t)(n0 + row) * K + k0 + cb,
                       smem + 4096 + c * 16);
        }
        __syncthreads();

        bf16x8_t a[2], b[4];
#pragma unroll
        for (int mi = 0; mi < 2; ++mi)
            a[mi] = *reinterpret_cast<const bf16x8_t*>(
                smem + ((wr * 32 + mi * 16 + lr) * 32 + kg * 8) * 2);
#pragma unroll
        for (int ni = 0; ni < 4; ++ni)
            b[ni] = *reinterpret_cast<const bf16x8_t*>(
                smem + 4096 + ((wc * 64 + ni * 16 + lr) * 32 + kg * 8) * 2);
#pragma unroll
        for (int mi = 0; mi < 2; ++mi)
#pragma unroll
            for (int ni = 0; ni < 4; ++ni)
                acc[mi][ni] = __builtin_amdgcn_mfma_f32_16x16x32_bf16(
                    a[mi], b[ni], acc[mi][ni], 0, 0, 0);
    }

    // epilogue: 2 passes of 32 rows (fp32) through LDS, bias in copy phase
    __syncthreads();
#pragma unroll
    for (int p = 0; p < 2; ++p) {
        if (p) __syncthreads();
        if (wr == p) {
#pragma unroll
            for (int mi = 0; mi < 2; ++mi)
#pragma unroll
                for (int ni = 0; ni < 4; ++ni) {
                    const int scol = wc * 64 + ni * 16 + lr;
#pragma unroll
                    for (int r = 0; r < 4; ++r) {
                        const int srow = mi * 16 + kg * 4 + r;
                        ((float*)smem)[srow * 128 + scol] = acc[mi][ni][r];
                    }
                }
        }
        __syncthreads();
#pragma unroll
        for (int cc = 0; cc < 4; ++cc) {
            const int chunk = tid + cc * 256;   // 1024 x 16B = [32][128] f32
            const int srow = chunk >> 5;
            const int sc = (chunk & 31) * 4;
            f32x4_t v = *reinterpret_cast<const f32x4_t*>(smem + chunk * 16);
            const f32x4_t bv = *reinterpret_cast<const f32x4_t*>(bias + n0 + sc);
            v += bv;
            *reinterpret_cast<f32x4_t*>(
                C + (size_t)(m0 + p * 32 + srow) * Nn + n0 + sc) = v;
        }
    }
}

// ---------------- banded MFMA attention --------------------------------------
__global__ __launch_bounds__(256) void attn_band_mfma(
    const __hip_bfloat16* __restrict__ qkv,
    __hip_bfloat16* __restrict__ ctx,
    const int* __restrict__ epoch_ptr)
{
    __shared__ __hip_bfloat16 P_lds[4][16 * 40];
    __shared__ __hip_bfloat16 V_lds[4][64 * 40];

    const int wave = threadIdx.x >> 6;
    const int lane = threadIdx.x & 63;
    const int lr = lane & 15, kg = lane >> 4;

    const int bid = blockIdx.x;
    const int tg = bid & 15;
    const int bh = bid >> 4;
    const int h = bh & 15, b = bh >> 4;
    const int i0 = (tg * 4 + wave) * 16;

    const int e = *epoch_ptr;
    int w;
    if      (e < 20) w = 6;
    else if (e < 30) w = 8;
    else if (e < 40) w = 10;
    else if (e < 50) w = 12;
    else             w = 1023;

    const size_t rowb = (size_t)b * 1024;
    const int hq = h * 192;

    bf16x8_t aq[2];
#pragma unroll
    for (int ks = 0; ks < 2; ++ks)
        aq[ks] = *(const bf16x8_t*)(qkv + (rowb + i0 + lr) * 3072 + hq + ks * 32 + kg * 8);

    float m[4] = {-1e30f, -1e30f, -1e30f, -1e30f};
    float l[4] = {0.f, 0.f, 0.f, 0.f};
    f32x4_t o[4] = {};

    int jlo = i0 - w;      if (jlo < 0) jlo = 0;
    int jhi = i0 + 15 + w; if (jhi > 1023) jhi = 1023;

    for (int p = (jlo >> 5); p <= (jhi >> 5); ++p) {
        const int kb = p * 32;

        const __hip_bfloat16* vbase0 = qkv + (rowb + kb + 2 * lr) * 3072 + hq + 128 + kg * 16;
        const __hip_bfloat16* vbase1 = vbase0 + 3072;
        u16x8_t va0 = *(const u16x8_t*)(vbase0);
        u16x8_t vb0 = *(const u16x8_t*)(vbase0 + 8);
        u16x8_t va1 = *(const u16x8_t*)(vbase1);
        u16x8_t vb1 = *(const u16x8_t*)(vbase1 + 8);

        f32x4_t s[2] = {};
#pragma unroll
        for (int t = 0; t < 2; ++t)
#pragma unroll
            for (int ks = 0; ks < 2; ++ks) {
                bf16x8_t bk = *(const bf16x8_t*)(
                    qkv + (rowb + kb + t * 16 + lr) * 3072 + hq + 64 + ks * 32 + kg * 8);
                s[t] = __builtin_amdgcn_mfma_f32_16x16x32_bf16(aq[ks], bk, s[t], 0, 0, 0);
            }

#pragma unroll
        for (int c = 0; c < 8; ++c) {
            unsigned int pk = (unsigned int)va0[c] | ((unsigned int)va1[c] << 16);
            *(unsigned int*)&V_lds[wave][(kg * 16 + c) * 40 + 2 * lr] = pk;
        }
#pragma unroll
        for (int c = 0; c < 8; ++c) {
            unsigned int pk = (unsigned int)vb0[c] | ((unsigned int)vb1[c] << 16);
            *(unsigned int*)&V_lds[wave][(kg * 16 + 8 + c) * 40 + 2 * lr] = pk;
        }

        float sv[2][4];
#pragma unroll
        for (int t = 0; t < 2; ++t)
#pragma unroll
            for (int r = 0; r < 4; ++r) {
                const int qi = i0 + kg * 4 + r;
                const int j  = kb + t * 16 + lr;
                int d = qi - j; if (d < 0) d = -d;
                sv[t][r] = (d <= w) ? s[t][r] * 0.125f : -1e30f;
            }

        float tm[4];
#pragma unroll
        for (int r = 0; r < 4; ++r) tm[r] = fmaxf(sv[0][r], sv[1][r]);
#pragma unroll
        for (int msk = 1; msk < 16; msk <<= 1)
#pragma unroll
            for (int r = 0; r < 4; ++r) tm[r] = fmaxf(tm[r], __shfl_xor(tm[r], msk));

        float sc[4], ps[4], pvv[2][4];
#pragma unroll
        for (int r = 0; r < 4; ++r) {
            const float mn = fmaxf(m[r], tm[r]);
            sc[r] = __expf(m[r] - mn);
            pvv[0][r] = __expf(sv[0][r] - mn);
            pvv[1][r] = __expf(sv[1][r] - mn);
            ps[r] = pvv[0][r] + pvv[1][r];
            m[r] = mn;
        }
#pragma unroll
        for (int msk = 1; msk < 16; msk <<= 1)
#pragma unroll
            for (int r = 0; r < 4; ++r) ps[r] += __shfl_xor(ps[r], msk);
#pragma unroll
        for (int r = 0; r < 4; ++r) l[r] = l[r] * sc[r] + ps[r];
#pragma unroll
        for (int ni = 0; ni < 4; ++ni)
#pragma unroll
            for (int r = 0; r < 4; ++r) o[ni][r] *= sc[r];

#pragma unroll
        for (int t = 0; t < 2; ++t)
#pragma unroll
            for (int r = 0; r < 4; ++r)
                P_lds[wave][(kg * 4 + r) * 40 + t * 16 + lr] =
                    __float2bfloat16(pvv[t][r]);

        bf16x8_t ap = *(const bf16x8_t*)&P_lds[wave][lr * 40 + kg * 8];
#pragma unroll
        for (int ni = 0; ni < 4; ++ni) {
            bf16x8_t bv = *(const bf16x8_t*)&V_lds[wave][(ni * 16 + lr) * 40 + kg * 8];
            o[ni] = __builtin_amdgcn_mfma_f32_16x16x32_bf16(ap, bv, o[ni], 0, 0, 0);
        }
    }

#pragma unroll
    for (int ni = 0; ni < 4; ++ni)
#pragma unroll
        for (int r = 0; r < 4; ++r)
            ctx[(rowb + i0 + kg * 4 + r) * 1024 + h * 64 + ni * 16 + lr] =
                __float2bfloat16(o[ni][r] / l[r]);
}

// ---------------- launch -----------------------------------------------------
extern "C" void kernel_launch(void* const* d_in, const int* in_sizes, int n_in,
                              void* d_out, int out_size, void* d_ws, size_t ws_size,
                              hipStream_t stream)
{
    const float* x     = (const float*)d_in[0];
    const float* Wqkv  = (const float*)d_in[1];
    const float* Wproj = (const float*)d_in[2];
    const float* bproj = (const float*)d_in[3];
    const int*   epoch = (const int*)d_in[4];

    char* ws = (char*)d_ws;
    __hip_bfloat16* xb     = (__hip_bfloat16*)(ws);
    __hip_bfloat16* wqkvb  = (__hip_bfloat16*)(ws + 8388608);
    __hip_bfloat16* wprojb = (__hip_bfloat16*)(ws + 8388608 + 6291456);
    __hip_bfloat16* qkvb   = (__hip_bfloat16*)(ws + 16777216);
    __hip_bfloat16* ctxb   = (__hip_bfloat16*)(ws + 16777216 + 25165824);

    convert_all<<<4096, 256, 0, stream>>>(x, Wqkv, Wproj, xb, wqkvb, wprojb);

    gemm1_qkv256<<<dim3(3072 / 256, 4096 / 256), 512, 0, stream>>>(
        xb, wqkvb, qkvb);

    attn_band_mfma<<<1024, 256, 0, stream>>>(qkvb, ctxb, epoch);

    gemm2_proj<<<dim3(1024 / 128, 4096 / 64), 256, 0, stream>>>(
        ctxb, wprojb, (float*)d_out, bproj);
}

// Round 6
// 76.250 us; speedup vs baseline: 2.0902x; 1.0302x over previous
//
#include <hip/hip_runtime.h>
#include <hip/hip_bf16.h>

// Problem: B=4, N=1024, C=1024, H=16, D=64.  epoch=25 -> band window w=8.
// Pipeline: convert->GEMM1(qkv, 256^2 pipelined + XCD super-tiles)
//           ->banded MFMA attention (block-shared K/V staging)->GEMM2(+bias).

typedef __bf16 bf16x8_t __attribute__((ext_vector_type(8)));
typedef unsigned short u16x8_t __attribute__((ext_vector_type(8)));
typedef float f32x4_t __attribute__((ext_vector_type(4)));

__device__ __forceinline__ void load_lds16(const void* g, void* l) {
    __builtin_amdgcn_global_load_lds(
        (__attribute__((address_space(1))) void*)(g),
        (__attribute__((address_space(3))) void*)(l),
        16, 0, 0);
}

// ---------------- fp32 -> bf16 conversion (x, Wqkv, Wproj fused) -------------
__global__ __launch_bounds__(256) void convert_all(
    const float* __restrict__ x, const float* __restrict__ wqkv,
    const float* __restrict__ wproj,
    __hip_bfloat16* __restrict__ xb, __hip_bfloat16* __restrict__ wqkvb,
    __hip_bfloat16* __restrict__ wprojb)
{
    const size_t t = (size_t)blockIdx.x * 256 + threadIdx.x;
    size_t i = t * 8;
    const float* src;
    __hip_bfloat16* dst;
    if (i < 4194304) {
        src = x; dst = xb;
    } else if (i < 4194304 + 3145728) {
        src = wqkv; dst = wqkvb; i -= 4194304;
    } else {
        src = wproj; dst = wprojb; i -= 4194304 + 3145728;
    }
    float4 v0 = *reinterpret_cast<const float4*>(src + i);
    float4 v1 = *reinterpret_cast<const float4*>(src + i + 4);
    union { u16x8_t v; __hip_bfloat16 h[8]; } u;
    u.h[0] = __float2bfloat16(v0.x); u.h[1] = __float2bfloat16(v0.y);
    u.h[2] = __float2bfloat16(v0.z); u.h[3] = __float2bfloat16(v0.w);
    u.h[4] = __float2bfloat16(v1.x); u.h[5] = __float2bfloat16(v1.y);
    u.h[6] = __float2bfloat16(v1.z); u.h[7] = __float2bfloat16(v1.w);
    *reinterpret_cast<u16x8_t*>(dst + i) = u.v;
}

// ---------------- GEMM1: qkv = xb @ WqkvT, bf16 out --------------------------
// 256x256 tile, 8 waves (2M x 4N), BK=32, 4-slot LDS rotation, counted vmcnt.
// XCD super-tile swizzle: each XCD owns 2 supers of 4m x 3n blocks (L2-sized).
__global__ __launch_bounds__(512, 2) void gemm1_qkv256(
    const __hip_bfloat16* __restrict__ A,   // [4096,1024]
    const __hip_bfloat16* __restrict__ B,   // [3072,1024]
    __hip_bfloat16* __restrict__ C)         // [4096,3072]
{
    __shared__ __align__(16) char smem[135168];
    const int tid = threadIdx.x;

    // XCD-chunked super-tile remap (bijective: 192 = 8 xcd * 2 supers * 12)
    const int orig = blockIdx.y * 12 + blockIdx.x;
    const int xcd = orig & 7, slot = orig >> 3;
    const int hi = (slot >= 12) ? 1 : 0;
    const int sup = xcd * 2 + hi;             // 16 supers: sm = sup&3, sn = sup>>2
    const int local = slot - hi * 12;         // 12 blocks per super: 4m x 3n
    const int m0 = ((sup & 3) * 4 + (local & 3)) * 256;
    const int n0 = ((sup >> 2) * 3 + (local >> 2)) * 256;

    const int wave = tid >> 6, lane = tid & 63;
    const int wr = wave >> 2, wc = wave & 3;
    const int lr = lane & 15, kg = lane >> 4;
    const int K = 1024, Nn = 3072;

    const int q0 = tid, q1 = tid + 512;
    const int ar0 = q0 >> 2, as0 = ((q0 & 3) ^ ((ar0 >> 1) & 3)) * 16;
    const int ar1 = q1 >> 2, as1 = ((q1 & 3) ^ ((ar1 >> 1) & 3)) * 16;
    const char* Asrc0 = (const char*)(A + (size_t)(m0 + ar0) * K) + as0;
    const char* Asrc1 = (const char*)(A + (size_t)(m0 + ar1) * K) + as1;
    const char* Bsrc0 = (const char*)(B + (size_t)(n0 + ar0) * K) + as0;
    const char* Bsrc1 = (const char*)(B + (size_t)(n0 + ar1) * K) + as1;

#define STAGE1(t) { const int sb_ = ((t) & 3) * 32768; const int ko_ = (t) * 64; \
    load_lds16(Asrc0 + ko_, smem + sb_ + q0 * 16);                               \
    load_lds16(Asrc1 + ko_, smem + sb_ + q1 * 16);                               \
    load_lds16(Bsrc0 + ko_, smem + sb_ + 16384 + q0 * 16);                       \
    load_lds16(Bsrc1 + ko_, smem + sb_ + 16384 + q1 * 16); }

    f32x4_t acc[8][4] = {};
    const int rsw = ((kg ^ ((lr >> 1) & 3)) * 16);
    const int arow = wr * 128 + lr;
    const int brow = wc * 64 + lr;

#define COMPUTE1(t) { const int sb_ = ((t) & 3) * 32768;                          \
    bf16x8_t a_[8], b_[4];                                                        \
    _Pragma("unroll") for (int mi = 0; mi < 8; ++mi)                              \
        a_[mi] = *(const bf16x8_t*)(smem + sb_ + (arow + mi * 16) * 64 + rsw);    \
    _Pragma("unroll") for (int ni = 0; ni < 4; ++ni)                              \
        b_[ni] = *(const bf16x8_t*)(smem + sb_ + 16384 + (brow + ni * 16) * 64 + rsw); \
    __builtin_amdgcn_s_setprio(1);                                                \
    _Pragma("unroll") for (int mi = 0; mi < 8; ++mi)                              \
    _Pragma("unroll") for (int ni = 0; ni < 4; ++ni)                              \
        acc[mi][ni] = __builtin_amdgcn_mfma_f32_16x16x32_bf16(                    \
            a_[mi], b_[ni], acc[mi][ni], 0, 0, 0);                                \
    __builtin_amdgcn_s_setprio(0); }

    STAGE1(0);
    STAGE1(1);
    for (int t = 0; t < 30; ++t) {
        STAGE1(t + 2);
        asm volatile("s_waitcnt vmcnt(8)" ::: "memory");
        __builtin_amdgcn_s_barrier();
        COMPUTE1(t);
    }
    asm volatile("s_waitcnt vmcnt(4)" ::: "memory");
    __builtin_amdgcn_s_barrier();
    COMPUTE1(30);
    asm volatile("s_waitcnt vmcnt(0)" ::: "memory");
    __builtin_amdgcn_s_barrier();
    COMPUTE1(31);
#undef STAGE1
#undef COMPUTE1

    __syncthreads();
    __hip_bfloat16* cl = (__hip_bfloat16*)smem;
#pragma unroll
    for (int mi = 0; mi < 8; ++mi)
#pragma unroll
        for (int ni = 0; ni < 4; ++ni)
#pragma unroll
            for (int r = 0; r < 4; ++r)
                cl[(wr * 128 + mi * 16 + kg * 4 + r) * 264 + wc * 64 + ni * 16 + lr] =
                    __float2bfloat16(acc[mi][ni][r]);
    __syncthreads();
#pragma unroll
    for (int c = 0; c < 16; ++c) {
        const int chunk = tid + c * 512;
        const int row = chunk >> 5, cc = chunk & 31;
        f32x4_t v = *(const f32x4_t*)(smem + row * 528 + cc * 16);
        *(f32x4_t*)((char*)C + ((size_t)(m0 + row) * Nn + n0) * 2 + cc * 16) = v;
    }
}

// ---------------- GEMM2: out = ctx @ WprojT + bias, fp32 out -----------------
// 64x128 tile, 512 blocks (2/CU), XCD-chunked remap (3 MB working set -> L2).
__global__ __launch_bounds__(256) void gemm2_proj(
    const __hip_bfloat16* __restrict__ A,   // ctx [4096,1024]
    const __hip_bfloat16* __restrict__ B,   // Wproj [1024,1024]
    float* __restrict__ C,                  // [4096,1024]
    const float* __restrict__ bias)
{
    __shared__ char smem[16384];
    const int tid = threadIdx.x;
    const int orig = blockIdx.y * 8 + blockIdx.x;
    const int wgid = (orig & 7) * 64 + (orig >> 3);   // bijective, 512%8==0
    const int n0 = (wgid & 7) * 128, m0 = (wgid >> 3) * 64;
    const int wave = tid >> 6, lane = tid & 63;
    const int wr = wave >> 1, wc = wave & 1;
    const int lr = lane & 15, kg = lane >> 4;
    const int K = 1024, Nn = 1024;

    f32x4_t acc[2][4] = {};

    for (int k0 = 0; k0 < K; k0 += 32) {
        __syncthreads();
        {
            const int row = tid >> 2, cb = (tid & 3) * 8;
            load_lds16(A + (size_t)(m0 + row) * K + k0 + cb, smem + tid * 16);
        }
#pragma unroll
        for (int it = 0; it < 2; ++it) {
            const int c = tid + it * 256;
            const int row = c >> 2, cb = (c & 3) * 8;
            load_lds16(B + (size_t)(n0 + row) * K + k0 + cb,
                       smem + 4096 + c * 16);
        }
        __syncthreads();

        bf16x8_t a[2], b[4];
#pragma unroll
        for (int mi = 0; mi < 2; ++mi)
            a[mi] = *reinterpret_cast<const bf16x8_t*>(
                smem + ((wr * 32 + mi * 16 + lr) * 32 + kg * 8) * 2);
#pragma unroll
        for (int ni = 0; ni < 4; ++ni)
            b[ni] = *reinterpret_cast<const bf16x8_t*>(
                smem + 4096 + ((wc * 64 + ni * 16 + lr) * 32 + kg * 8) * 2);
#pragma unroll
        for (int mi = 0; mi < 2; ++mi)
#pragma unroll
            for (int ni = 0; ni < 4; ++ni)
                acc[mi][ni] = __builtin_amdgcn_mfma_f32_16x16x32_bf16(
                    a[mi], b[ni], acc[mi][ni], 0, 0, 0);
    }

    __syncthreads();
#pragma unroll
    for (int p = 0; p < 2; ++p) {
        if (p) __syncthreads();
        if (wr == p) {
#pragma unroll
            for (int mi = 0; mi < 2; ++mi)
#pragma unroll
                for (int ni = 0; ni < 4; ++ni) {
                    const int scol = wc * 64 + ni * 16 + lr;
#pragma unroll
                    for (int r = 0; r < 4; ++r) {
                        const int srow = mi * 16 + kg * 4 + r;
                        ((float*)smem)[srow * 128 + scol] = acc[mi][ni][r];
                    }
                }
        }
        __syncthreads();
#pragma unroll
        for (int cc = 0; cc < 4; ++cc) {
            const int chunk = tid + cc * 256;
            const int srow = chunk >> 5;
            const int sc = (chunk & 31) * 4;
            f32x4_t v = *reinterpret_cast<const f32x4_t*>(smem + chunk * 16);
            const f32x4_t bv = *reinterpret_cast<const f32x4_t*>(bias + n0 + sc);
            v += bv;
            *reinterpret_cast<f32x4_t*>(
                C + (size_t)(m0 + p * 32 + srow) * Nn + n0 + sc) = v;
        }
    }
}

// ---------------- banded MFMA attention, block-shared K/V --------------------
// Block = 64 queries of one (b,h) = 4 waves x 16.  Band union = 4 aligned
// 32-key tiles (128 keys).  K staged once via global_load_lds (XOR-swizzled
// chunks: slot = chunk ^ (row&7)); V^T staged once via packed reg-transpose
// into [64][136] (272 B rows -> 2-way-free b128 reads).
__global__ __launch_bounds__(256) void attn_band_mfma(
    const __hip_bfloat16* __restrict__ qkv,
    __hip_bfloat16* __restrict__ ctx,
    const int* __restrict__ epoch_ptr)
{
    __shared__ __align__(16) __hip_bfloat16 K_lds[128 * 64];   // 16 KB
    __shared__ __align__(16) __hip_bfloat16 V_lds[64 * 136];   // 17 KB, V^T
    __shared__ __hip_bfloat16 P_lds[4][16 * 40];               // 5 KB

    const int tid = threadIdx.x;
    const int wave = tid >> 6, lane = tid & 63;
    const int lr = lane & 15, kg = lane >> 4;

    const int bid = blockIdx.x;          // b*256 + h*16 + tg
    const int tg = bid & 15;
    const int bh = bid >> 4;
    const int h = bh & 15, b = bh >> 4;
    const int base = tg * 64;
    const int i0 = base + wave * 16;

    const int e = *epoch_ptr;
    int w;
    if      (e < 20) w = 6;
    else if (e < 30) w = 8;
    else if (e < 40) w = 10;
    else if (e < 50) w = 12;
    else             w = 1023;

    const size_t rowb = (size_t)b * 1024;
    const int hq = h * 192;

    // ---- stage K rows [base-32, base+96) (clamped addresses; clamped rows
    // are never read: tl range keeps all consumed j in [0,1023])
#pragma unroll
    for (int it = 0; it < 4; ++it) {
        const int q = tid + it * 256;
        const int row = q >> 3, s = q & 7;
        const int c = s ^ (row & 7);
        int gk = base - 32 + row;
        gk = gk < 0 ? 0 : (gk > 1023 ? 1023 : gk);
        load_lds16(qkv + (rowb + gk) * 3072 + hq + 64 + c * 8,
                   (char*)K_lds + q * 16);
    }
    // ---- stage V^T: thread = (key-pair pr, dim-group dg)
    {
        const int pr = tid & 63, dg = tid >> 6;
        int gk0 = base - 32 + 2 * pr, gk1 = gk0 + 1;
        gk0 = gk0 < 0 ? 0 : (gk0 > 1023 ? 1023 : gk0);
        gk1 = gk1 < 0 ? 0 : (gk1 > 1023 ? 1023 : gk1);
        const __hip_bfloat16* v0 = qkv + (rowb + gk0) * 3072 + hq + 128 + dg * 16;
        const __hip_bfloat16* v1 = qkv + (rowb + gk1) * 3072 + hq + 128 + dg * 16;
        u16x8_t a0 = *(const u16x8_t*)v0, b0 = *(const u16x8_t*)(v0 + 8);
        u16x8_t a1 = *(const u16x8_t*)v1, b1 = *(const u16x8_t*)(v1 + 8);
#pragma unroll
        for (int c2 = 0; c2 < 8; ++c2) {
            *(unsigned int*)&V_lds[(dg * 16 + c2) * 136 + 2 * pr] =
                (unsigned int)a0[c2] | ((unsigned int)a1[c2] << 16);
            *(unsigned int*)&V_lds[(dg * 16 + 8 + c2) * 136 + 2 * pr] =
                (unsigned int)b0[c2] | ((unsigned int)b1[c2] << 16);
        }
    }

    // Q fragments (global, per wave)
    bf16x8_t aq[2];
#pragma unroll
    for (int ks = 0; ks < 2; ++ks)
        aq[ks] = *(const bf16x8_t*)(qkv + (rowb + i0 + lr) * 3072 + hq + ks * 32 + kg * 8);

    __syncthreads();

    float m[4] = {-1e30f, -1e30f, -1e30f, -1e30f};
    float l[4] = {0.f, 0.f, 0.f, 0.f};
    f32x4_t o[4] = {};

    int jlo = i0 - w;      if (jlo < 0) jlo = 0;
    int jhi = i0 + 15 + w; if (jhi > 1023) jhi = 1023;
    const int t0 = (base >> 5) - 1;

    for (int p = (jlo >> 5); p <= (jhi >> 5); ++p) {
        const int kb = p * 32;
        const int tl = p - t0;     // local tile 0..3

        // ---- S = Q K^T from shared K
        f32x4_t s2[2] = {};
#pragma unroll
        for (int t = 0; t < 2; ++t)
#pragma unroll
            for (int ks = 0; ks < 2; ++ks) {
                const int lkr = tl * 32 + t * 16 + lr;
                bf16x8_t bk = *(const bf16x8_t*)(
                    (char*)K_lds + lkr * 128 + (((ks * 4 + kg) ^ (lr & 7)) * 16));
                s2[t] = __builtin_amdgcn_mfma_f32_16x16x32_bf16(aq[ks], bk, s2[t], 0, 0, 0);
            }

        // ---- scale + band mask
        float sv[2][4];
#pragma unroll
        for (int t = 0; t < 2; ++t)
#pragma unroll
            for (int r = 0; r < 4; ++r) {
                const int qi = i0 + kg * 4 + r;
                const int j  = kb + t * 16 + lr;
                int d = qi - j; if (d < 0) d = -d;
                sv[t][r] = (d <= w) ? s2[t][r] * 0.125f : -1e30f;
            }

        // ---- row max across 16 key lanes
        float tm[4];
#pragma unroll
        for (int r = 0; r < 4; ++r) tm[r] = fmaxf(sv[0][r], sv[1][r]);
#pragma unroll
        for (int msk = 1; msk < 16; msk <<= 1)
#pragma unroll
            for (int r = 0; r < 4; ++r) tm[r] = fmaxf(tm[r], __shfl_xor(tm[r], msk));

        // ---- online softmax update
        float sc[4], ps[4], pvv[2][4];
#pragma unroll
        for (int r = 0; r < 4; ++r) {
            const float mn = fmaxf(m[r], tm[r]);
            sc[r] = __expf(m[r] - mn);
            pvv[0][r] = __expf(sv[0][r] - mn);
            pvv[1][r] = __expf(sv[1][r] - mn);
            ps[r] = pvv[0][r] + pvv[1][r];
            m[r] = mn;
        }
#pragma unroll
        for (int msk = 1; msk < 16; msk <<= 1)
#pragma unroll
            for (int r = 0; r < 4; ++r) ps[r] += __shfl_xor(ps[r], msk);
#pragma unroll
        for (int r = 0; r < 4; ++r) l[r] = l[r] * sc[r] + ps[r];
#pragma unroll
        for (int ni = 0; ni < 4; ++ni)
#pragma unroll
            for (int r = 0; r < 4; ++r) o[ni][r] *= sc[r];

        // ---- P -> LDS (bf16), per-wave region
#pragma unroll
        for (int t = 0; t < 2; ++t)
#pragma unroll
            for (int r = 0; r < 4; ++r)
                P_lds[wave][(kg * 4 + r) * 40 + t * 16 + lr] =
                    __float2bfloat16(pvv[t][r]);

        // ---- PV from shared V^T
        bf16x8_t ap = *(const bf16x8_t*)&P_lds[wave][lr * 40 + kg * 8];
#pragma unroll
        for (int ni = 0; ni < 4; ++ni) {
            bf16x8_t bv = *(const bf16x8_t*)&V_lds[(ni * 16 + lr) * 136 + tl * 32 + kg * 8];
            o[ni] = __builtin_amdgcn_mfma_f32_16x16x32_bf16(ap, bv, o[ni], 0, 0, 0);
        }
    }

#pragma unroll
    for (int ni = 0; ni < 4; ++ni)
#pragma unroll
        for (int r = 0; r < 4; ++r)
            ctx[(rowb + i0 + kg * 4 + r) * 1024 + h * 64 + ni * 16 + lr] =
                __float2bfloat16(o[ni][r] / l[r]);
}

// ---------------- launch -----------------------------------------------------
extern "C" void kernel_launch(void* const* d_in, const int* in_sizes, int n_in,
                              void* d_out, int out_size, void* d_ws, size_t ws_size,
                              hipStream_t stream)
{
    const float* x     = (const float*)d_in[0];
    const float* Wqkv  = (const float*)d_in[1];
    const float* Wproj = (const float*)d_in[2];
    const float* bproj = (const float*)d_in[3];
    const int*   epoch = (const int*)d_in[4];

    char* ws = (char*)d_ws;
    __hip_bfloat16* xb     = (__hip_bfloat16*)(ws);
    __hip_bfloat16* wqkvb  = (__hip_bfloat16*)(ws + 8388608);
    __hip_bfloat16* wprojb = (__hip_bfloat16*)(ws + 8388608 + 6291456);
    __hip_bfloat16* qkvb   = (__hip_bfloat16*)(ws + 16777216);
    __hip_bfloat16* ctxb   = (__hip_bfloat16*)(ws + 16777216 + 25165824);

    convert_all<<<4096, 256, 0, stream>>>(x, Wqkv, Wproj, xb, wqkvb, wprojb);

    gemm1_qkv256<<<dim3(3072 / 256, 4096 / 256), 512, 0, stream>>>(
        xb, wqkvb, qkvb);

    attn_band_mfma<<<1024, 256, 0, stream>>>(qkvb, ctxb, epoch);

    gemm2_proj<<<dim3(1024 / 128, 4096 / 64), 256, 0, stream>>>(
        ctxb, wprojb, (float*)d_out, bproj);
}

// Round 7
// 73.634 us; speedup vs baseline: 2.1645x; 1.0355x over previous
//
#include <hip/hip_runtime.h>
#include <hip/hip_bf16.h>

// Problem: B=4, N=1024, C=1024, H=16, D=64.  epoch=25 -> band window w=8.
// Pipeline: convert->GEMM1(qkv, 256x192 tiles = 256 blocks, pipelined)
//           ->banded MFMA attention (block-shared K/V)->GEMM2(+bias).

typedef __bf16 bf16x8_t __attribute__((ext_vector_type(8)));
typedef unsigned short u16x8_t __attribute__((ext_vector_type(8)));
typedef float f32x4_t __attribute__((ext_vector_type(4)));

__device__ __forceinline__ void load_lds16(const void* g, void* l) {
    __builtin_amdgcn_global_load_lds(
        (__attribute__((address_space(1))) void*)(g),
        (__attribute__((address_space(3))) void*)(l),
        16, 0, 0);
}

// ---------------- fp32 -> bf16 conversion (x, Wqkv, Wproj fused) -------------
__global__ __launch_bounds__(256) void convert_all(
    const float* __restrict__ x, const float* __restrict__ wqkv,
    const float* __restrict__ wproj,
    __hip_bfloat16* __restrict__ xb, __hip_bfloat16* __restrict__ wqkvb,
    __hip_bfloat16* __restrict__ wprojb)
{
    const size_t t = (size_t)blockIdx.x * 256 + threadIdx.x;
    size_t i = t * 8;
    const float* src;
    __hip_bfloat16* dst;
    if (i < 4194304) {
        src = x; dst = xb;
    } else if (i < 4194304 + 3145728) {
        src = wqkv; dst = wqkvb; i -= 4194304;
    } else {
        src = wproj; dst = wprojb; i -= 4194304 + 3145728;
    }
    float4 v0 = *reinterpret_cast<const float4*>(src + i);
    float4 v1 = *reinterpret_cast<const float4*>(src + i + 4);
    union { u16x8_t v; __hip_bfloat16 h[8]; } u;
    u.h[0] = __float2bfloat16(v0.x); u.h[1] = __float2bfloat16(v0.y);
    u.h[2] = __float2bfloat16(v0.z); u.h[3] = __float2bfloat16(v0.w);
    u.h[4] = __float2bfloat16(v1.x); u.h[5] = __float2bfloat16(v1.y);
    u.h[6] = __float2bfloat16(v1.z); u.h[7] = __float2bfloat16(v1.w);
    *reinterpret_cast<u16x8_t*>(dst + i) = u.v;
}

// ---------------- GEMM1: qkv = xb @ WqkvT, bf16 out --------------------------
// 256x192 tile -> grid 16x16 = 256 blocks = 1/CU (100% coverage; was 192).
// 8 waves (2M x 4N, 128x48 each), BK=32, 4-slot LDS rotation, counted vmcnt.
// Loads/stage: waves 0-3: 2A+2B=4, waves 4-7: 2A+1B=3 -> vmcnt(6)/(3)/(0).
__global__ __launch_bounds__(512, 2) void gemm1_qkv256(
    const __hip_bfloat16* __restrict__ A,   // [4096,1024]
    const __hip_bfloat16* __restrict__ B,   // [3072,1024]
    __hip_bfloat16* __restrict__ C)         // [4096,3072]
{
    __shared__ __align__(16) char smem[114688];   // 4 slots x (16KB A + 12KB B)
    const int tid = threadIdx.x;

    // XCD-chunked 4x4 super-tiles (A 2MB + B 1.5MB per super ~ L2).
    // Bijective: 256 = 8 xcd * 2 supers * 16 blocks.
    const int orig = blockIdx.y * 16 + blockIdx.x;
    const int xcd = orig & 7, slot = orig >> 3;   // slot 0..31
    const int hi = slot >> 4;
    const int s  = xcd * 2 + hi;                  // super 0..15 (4m x 4n)
    const int w  = slot & 15;                     // local 0..15 (4m x 4n)
    const int m0 = ((s & 3) * 4 + (w & 3)) * 256;
    const int n0 = ((s >> 2) * 4 + (w >> 2)) * 192;

    const int wave = tid >> 6, lane = tid & 63;
    const int wr = wave >> 2, wc = wave & 3;
    const int lr = lane & 15, kg = lane >> 4;
    const int K = 1024, Nn = 3072;

    // A tile: 256 rows x 64B = 1024 chunks (2/thread).
    // B tile: 192 rows x 64B = 768 chunks (tid<512: 1; tid>=256: +1).
    const int qa0 = tid, qa1 = tid + 512;
    const int qb0 = tid, qb1 = tid + 256;
    const int ra0 = qa0 >> 2, sa0 = ((qa0 & 3) ^ ((ra0 >> 1) & 3)) * 16;
    const int ra1 = qa1 >> 2, sa1 = ((qa1 & 3) ^ ((ra1 >> 1) & 3)) * 16;
    const int rb0 = qb0 >> 2, sb0 = ((qb0 & 3) ^ ((rb0 >> 1) & 3)) * 16;
    const int rb1 = qb1 >> 2, sb1 = ((qb1 & 3) ^ ((rb1 >> 1) & 3)) * 16;
    const char* Asrc0 = (const char*)(A + (size_t)(m0 + ra0) * K) + sa0;
    const char* Asrc1 = (const char*)(A + (size_t)(m0 + ra1) * K) + sa1;
    const char* Bsrc0 = (const char*)(B + (size_t)(n0 + rb0) * K) + sb0;
    const char* Bsrc1 = (const char*)(B + (size_t)(n0 + rb1) * K) + sb1;
    const bool bextra = (tid >= 256);             // wave-uniform

#define STAGE1(t) { const int sb_ = ((t) & 3) * 28672; const int ko_ = (t) * 64;  \
    load_lds16(Asrc0 + ko_, smem + sb_ + qa0 * 16);                                \
    load_lds16(Asrc1 + ko_, smem + sb_ + qa1 * 16);                                \
    load_lds16(Bsrc0 + ko_, smem + sb_ + 16384 + qb0 * 16);                        \
    if (bextra) load_lds16(Bsrc1 + ko_, smem + sb_ + 16384 + qb1 * 16); }

    f32x4_t acc[8][3] = {};
    const int rsw = ((kg ^ ((lr >> 1) & 3)) * 16);
    const int arow = wr * 128 + lr;
    const int brow = wc * 48 + lr;

#define COMPUTE1(t) { const int sb_ = ((t) & 3) * 28672;                           \
    bf16x8_t a_[8], b_[3];                                                         \
    _Pragma("unroll") for (int mi = 0; mi < 8; ++mi)                               \
        a_[mi] = *(const bf16x8_t*)(smem + sb_ + (arow + mi * 16) * 64 + rsw);     \
    _Pragma("unroll") for (int ni = 0; ni < 3; ++ni)                               \
        b_[ni] = *(const bf16x8_t*)(smem + sb_ + 16384 + (brow + ni * 16) * 64 + rsw); \
    __builtin_amdgcn_s_setprio(1);                                                 \
    _Pragma("unroll") for (int mi = 0; mi < 8; ++mi)                               \
    _Pragma("unroll") for (int ni = 0; ni < 3; ++ni)                               \
        acc[mi][ni] = __builtin_amdgcn_mfma_f32_16x16x32_bf16(                     \
            a_[mi], b_[ni], acc[mi][ni], 0, 0, 0);                                 \
    __builtin_amdgcn_s_setprio(0); }

    STAGE1(0);
    STAGE1(1);
    for (int t = 0; t < 30; ++t) {
        STAGE1(t + 2);
        asm volatile("s_waitcnt vmcnt(6)" ::: "memory");   // stage t landed (both classes)
        __builtin_amdgcn_s_barrier();
        COMPUTE1(t);
    }
    asm volatile("s_waitcnt vmcnt(3)" ::: "memory");
    __builtin_amdgcn_s_barrier();
    COMPUTE1(30);
    asm volatile("s_waitcnt vmcnt(0)" ::: "memory");
    __builtin_amdgcn_s_barrier();
    COMPUTE1(31);
#undef STAGE1
#undef COMPUTE1

    // epilogue via LDS [256][200] bf16 (400B rows), 16B coalesced stores
    __syncthreads();
    __hip_bfloat16* cl = (__hip_bfloat16*)smem;
#pragma unroll
    for (int mi = 0; mi < 8; ++mi)
#pragma unroll
        for (int ni = 0; ni < 3; ++ni)
#pragma unroll
            for (int r = 0; r < 4; ++r)
                cl[(wr * 128 + mi * 16 + kg * 4 + r) * 200 + wc * 48 + ni * 16 + lr] =
                    __float2bfloat16(acc[mi][ni][r]);
    __syncthreads();
#pragma unroll
    for (int c = 0; c < 12; ++c) {
        const int id = tid + c * 512;        // 6144 = 256 rows x 24 chunks
        const int row = id / 24, cc = id - row * 24;
        f32x4_t v = *(const f32x4_t*)(smem + row * 400 + cc * 16);
        *(f32x4_t*)((char*)C + ((size_t)(m0 + row) * Nn + n0) * 2 + cc * 16) = v;
    }
}

// ---------------- GEMM2: out = ctx @ WprojT + bias, fp32 out -----------------
__global__ __launch_bounds__(256) void gemm2_proj(
    const __hip_bfloat16* __restrict__ A,   // ctx [4096,1024]
    const __hip_bfloat16* __restrict__ B,   // Wproj [1024,1024]
    float* __restrict__ C,                  // [4096,1024]
    const float* __restrict__ bias)
{
    __shared__ char smem[16384];
    const int tid = threadIdx.x;
    const int orig = blockIdx.y * 8 + blockIdx.x;
    const int wgid = (orig & 7) * 64 + (orig >> 3);
    const int n0 = (wgid & 7) * 128, m0 = (wgid >> 3) * 64;
    const int wave = tid >> 6, lane = tid & 63;
    const int wr = wave >> 1, wc = wave & 1;
    const int lr = lane & 15, kg = lane >> 4;
    const int K = 1024, Nn = 1024;

    f32x4_t acc[2][4] = {};

    for (int k0 = 0; k0 < K; k0 += 32) {
        __syncthreads();
        {
            const int row = tid >> 2, cb = (tid & 3) * 8;
            load_lds16(A + (size_t)(m0 + row) * K + k0 + cb, smem + tid * 16);
        }
#pragma unroll
        for (int it = 0; it < 2; ++it) {
            const int c = tid + it * 256;
            const int row = c >> 2, cb = (c & 3) * 8;
            load_lds16(B + (size_t)(n0 + row) * K + k0 + cb,
                       smem + 4096 + c * 16);
        }
        __syncthreads();

        bf16x8_t a[2], b[4];
#pragma unroll
        for (int mi = 0; mi < 2; ++mi)
            a[mi] = *reinterpret_cast<const bf16x8_t*>(
                smem + ((wr * 32 + mi * 16 + lr) * 32 + kg * 8) * 2);
#pragma unroll
        for (int ni = 0; ni < 4; ++ni)
            b[ni] = *reinterpret_cast<const bf16x8_t*>(
                smem + 4096 + ((wc * 64 + ni * 16 + lr) * 32 + kg * 8) * 2);
#pragma unroll
        for (int mi = 0; mi < 2; ++mi)
#pragma unroll
            for (int ni = 0; ni < 4; ++ni)
                acc[mi][ni] = __builtin_amdgcn_mfma_f32_16x16x32_bf16(
                    a[mi], b[ni], acc[mi][ni], 0, 0, 0);
    }

    __syncthreads();
#pragma unroll
    for (int p = 0; p < 2; ++p) {
        if (p) __syncthreads();
        if (wr == p) {
#pragma unroll
            for (int mi = 0; mi < 2; ++mi)
#pragma unroll
                for (int ni = 0; ni < 4; ++ni) {
                    const int scol = wc * 64 + ni * 16 + lr;
#pragma unroll
                    for (int r = 0; r < 4; ++r) {
                        const int srow = mi * 16 + kg * 4 + r;
                        ((float*)smem)[srow * 128 + scol] = acc[mi][ni][r];
                    }
                }
        }
        __syncthreads();
#pragma unroll
        for (int cc = 0; cc < 4; ++cc) {
            const int chunk = tid + cc * 256;
            const int srow = chunk >> 5;
            const int sc = (chunk & 31) * 4;
            f32x4_t v = *reinterpret_cast<const f32x4_t*>(smem + chunk * 16);
            const f32x4_t bv = *reinterpret_cast<const f32x4_t*>(bias + n0 + sc);
            v += bv;
            *reinterpret_cast<f32x4_t*>(
                C + (size_t)(m0 + p * 32 + srow) * Nn + n0 + sc) = v;
        }
    }
}

// ---------------- banded MFMA attention, block-shared K/V --------------------
__global__ __launch_bounds__(256) void attn_band_mfma(
    const __hip_bfloat16* __restrict__ qkv,
    __hip_bfloat16* __restrict__ ctx,
    const int* __restrict__ epoch_ptr)
{
    __shared__ __align__(16) __hip_bfloat16 K_lds[128 * 64];   // 16 KB
    __shared__ __align__(16) __hip_bfloat16 V_lds[64 * 136];   // 17 KB, V^T
    __shared__ __hip_bfloat16 P_lds[4][16 * 40];               // 5 KB

    const int tid = threadIdx.x;
    const int wave = tid >> 6, lane = tid & 63;
    const int lr = lane & 15, kg = lane >> 4;

    const int bid = blockIdx.x;          // b*256 + h*16 + tg
    const int tg = bid & 15;
    const int bh = bid >> 4;
    const int h = bh & 15, b = bh >> 4;
    const int base = tg * 64;
    const int i0 = base + wave * 16;

    const int e = *epoch_ptr;
    int w;
    if      (e < 20) w = 6;
    else if (e < 30) w = 8;
    else if (e < 40) w = 10;
    else if (e < 50) w = 12;
    else             w = 1023;

    const size_t rowb = (size_t)b * 1024;
    const int hq = h * 192;

#pragma unroll
    for (int it = 0; it < 4; ++it) {
        const int q = tid + it * 256;
        const int row = q >> 3, s = q & 7;
        const int c = s ^ (row & 7);
        int gk = base - 32 + row;
        gk = gk < 0 ? 0 : (gk > 1023 ? 1023 : gk);
        load_lds16(qkv + (rowb + gk) * 3072 + hq + 64 + c * 8,
                   (char*)K_lds + q * 16);
    }
    {
        const int pr = tid & 63, dg = tid >> 6;
        int gk0 = base - 32 + 2 * pr, gk1 = gk0 + 1;
        gk0 = gk0 < 0 ? 0 : (gk0 > 1023 ? 1023 : gk0);
        gk1 = gk1 < 0 ? 0 : (gk1 > 1023 ? 1023 : gk1);
        const __hip_bfloat16* v0 = qkv + (rowb + gk0) * 3072 + hq + 128 + dg * 16;
        const __hip_bfloat16* v1 = qkv + (rowb + gk1) * 3072 + hq + 128 + dg * 16;
        u16x8_t a0 = *(const u16x8_t*)v0, b0 = *(const u16x8_t*)(v0 + 8);
        u16x8_t a1 = *(const u16x8_t*)v1, b1 = *(const u16x8_t*)(v1 + 8);
#pragma unroll
        for (int c2 = 0; c2 < 8; ++c2) {
            *(unsigned int*)&V_lds[(dg * 16 + c2) * 136 + 2 * pr] =
                (unsigned int)a0[c2] | ((unsigned int)a1[c2] << 16);
            *(unsigned int*)&V_lds[(dg * 16 + 8 + c2) * 136 + 2 * pr] =
                (unsigned int)b0[c2] | ((unsigned int)b1[c2] << 16);
        }
    }

    bf16x8_t aq[2];
#pragma unroll
    for (int ks = 0; ks < 2; ++ks)
        aq[ks] = *(const bf16x8_t*)(qkv + (rowb + i0 + lr) * 3072 + hq + ks * 32 + kg * 8);

    __syncthreads();

    float m[4] = {-1e30f, -1e30f, -1e30f, -1e30f};
    float l[4] = {0.f, 0.f, 0.f, 0.f};
    f32x4_t o[4] = {};

    int jlo = i0 - w;      if (jlo < 0) jlo = 0;
    int jhi = i0 + 15 + w; if (jhi > 1023) jhi = 1023;
    const int t0 = (base >> 5) - 1;

    for (int p = (jlo >> 5); p <= (jhi >> 5); ++p) {
        const int kb = p * 32;
        const int tl = p - t0;

        f32x4_t s2[2] = {};
#pragma unroll
        for (int t = 0; t < 2; ++t)
#pragma unroll
            for (int ks = 0; ks < 2; ++ks) {
                const int lkr = tl * 32 + t * 16 + lr;
                bf16x8_t bk = *(const bf16x8_t*)(
                    (char*)K_lds + lkr * 128 + (((ks * 4 + kg) ^ (lr & 7)) * 16));
                s2[t] = __builtin_amdgcn_mfma_f32_16x16x32_bf16(aq[ks], bk, s2[t], 0, 0, 0);
            }

        float sv[2][4];
#pragma unroll
        for (int t = 0; t < 2; ++t)
#pragma unroll
            for (int r = 0; r < 4; ++r) {
                const int qi = i0 + kg * 4 + r;
                const int j  = kb + t * 16 + lr;
                int d = qi - j; if (d < 0) d = -d;
                sv[t][r] = (d <= w) ? s2[t][r] * 0.125f : -1e30f;
            }

        float tm[4];
#pragma unroll
        for (int r = 0; r < 4; ++r) tm[r] = fmaxf(sv[0][r], sv[1][r]);
#pragma unroll
        for (int msk = 1; msk < 16; msk <<= 1)
#pragma unroll
            for (int r = 0; r < 4; ++r) tm[r] = fmaxf(tm[r], __shfl_xor(tm[r], msk));

        float sc[4], ps[4], pvv[2][4];
#pragma unroll
        for (int r = 0; r < 4; ++r) {
            const float mn = fmaxf(m[r], tm[r]);
            sc[r] = __expf(m[r] - mn);
            pvv[0][r] = __expf(sv[0][r] - mn);
            pvv[1][r] = __expf(sv[1][r] - mn);
            ps[r] = pvv[0][r] + pvv[1][r];
            m[r] = mn;
        }
#pragma unroll
        for (int msk = 1; msk < 16; msk <<= 1)
#pragma unroll
            for (int r = 0; r < 4; ++r) ps[r] += __shfl_xor(ps[r], msk);
#pragma unroll
        for (int r = 0; r < 4; ++r) l[r] = l[r] * sc[r] + ps[r];
#pragma unroll
        for (int ni = 0; ni < 4; ++ni)
#pragma unroll
            for (int r = 0; r < 4; ++r) o[ni][r] *= sc[r];

#pragma unroll
        for (int t = 0; t < 2; ++t)
#pragma unroll
            for (int r = 0; r < 4; ++r)
                P_lds[wave][(kg * 4 + r) * 40 + t * 16 + lr] =
                    __float2bfloat16(pvv[t][r]);

        bf16x8_t ap = *(const bf16x8_t*)&P_lds[wave][lr * 40 + kg * 8];
#pragma unroll
        for (int ni = 0; ni < 4; ++ni) {
            bf16x8_t bv = *(const bf16x8_t*)&V_lds[(ni * 16 + lr) * 136 + tl * 32 + kg * 8];
            o[ni] = __builtin_amdgcn_mfma_f32_16x16x32_bf16(ap, bv, o[ni], 0, 0, 0);
        }
    }

#pragma unroll
    for (int ni = 0; ni < 4; ++ni)
#pragma unroll
        for (int r = 0; r < 4; ++r)
            ctx[(rowb + i0 + kg * 4 + r) * 1024 + h * 64 + ni * 16 + lr] =
                __float2bfloat16(o[ni][r] / l[r]);
}

// ---------------- launch -----------------------------------------------------
extern "C" void kernel_launch(void* const* d_in, const int* in_sizes, int n_in,
                              void* d_out, int out_size, void* d_ws, size_t ws_size,
                              hipStream_t stream)
{
    const float* x     = (const float*)d_in[0];
    const float* Wqkv  = (const float*)d_in[1];
    const float* Wproj = (const float*)d_in[2];
    const float* bproj = (const float*)d_in[3];
    const int*   epoch = (const int*)d_in[4];

    char* ws = (char*)d_ws;
    __hip_bfloat16* xb     = (__hip_bfloat16*)(ws);
    __hip_bfloat16* wqkvb  = (__hip_bfloat16*)(ws + 8388608);
    __hip_bfloat16* wprojb = (__hip_bfloat16*)(ws + 8388608 + 6291456);
    __hip_bfloat16* qkvb   = (__hip_bfloat16*)(ws + 16777216);
    __hip_bfloat16* ctxb   = (__hip_bfloat16*)(ws + 16777216 + 25165824);

    convert_all<<<4096, 256, 0, stream>>>(x, Wqkv, Wproj, xb, wqkvb, wprojb);

    gemm1_qkv256<<<dim3(16, 16), 512, 0, stream>>>(xb, wqkvb, qkvb);

    attn_band_mfma<<<1024, 256, 0, stream>>>(qkvb, ctxb, epoch);

    gemm2_proj<<<dim3(1024 / 128, 4096 / 64), 256, 0, stream>>>(
        ctxb, wprojb, (float*)d_out, bproj);
}